// Round 1
// baseline (7420.260 us; speedup 1.0000x reference)
//
#include <hip/hip_runtime.h>

// Problem constants
#define N_NODES 16384
#define C_DIM   128
#define E_EDGES 262144
#define S_SPEC  10

__device__ __constant__ const float INV_C     = 0.08838834764831845f;  // 1/sqrt(128)
__device__ __constant__ const float INV_2C    = 0.0625f;               // 1/sqrt(256)
#define F_INV_SQRT3 0.5773502691896258f
#define F_INV_SQRT8 0.35355339059327373f
#define F_INV_AVG   0.0625f   // 1/16 neighbors

__device__ __forceinline__ float silu(float x) {
    return x / (1.0f + __expf(-x));
}

// ---------------------------------------------------------------------------
// Kernel A: per-node "pre" transforms.
//   sc_s[n,d]   = sum_c s_in[n,c]  *W_sc0[spec][c,d] * inv_c   (out comp 0)
//   sc_v[n,d,i] = sum_c v_in[n,c,i]*W_sc1[spec][c,d] * inv_c   (out comps 1..3)
//   s[n,d]      = sum_c s_in[n,c]  *W_pre0[c,d] * inv_c        (ws comp 0)
//   v[n,d,i]    = sum_c v_in[n,c,i]*W_pre1[c,d] * inv_c        (ws comps 1..3)
// 8 nodes per block, thread t: d = t&127, half = t>>7 owns 4 nodes.
// ---------------------------------------------------------------------------
__global__ __launch_bounds__(256) void node_pre_kernel(
    const int* __restrict__ specie,
    const float* __restrict__ node_feats,   // [N][C][4]
    const float* __restrict__ Wsc0,         // [S][C][C]
    const float* __restrict__ Wsc1,
    const float* __restrict__ Wpre0,        // [C][C]
    const float* __restrict__ Wpre1,
    float* __restrict__ out_sc,             // [N][C][4] (second output)
    float* __restrict__ sv)                 // [N][C][4] workspace
{
    __shared__ float4 in_lds[8][C_DIM];     // [node][c] = (s, v0, v1, v2)
    const int n0 = blockIdx.x * 8;
    const int t  = threadIdx.x;

    const float4* nf4 = (const float4*)node_feats;
    for (int idx = t; idx < 8 * C_DIM; idx += 256) {
        int nn = idx >> 7, c = idx & 127;
        in_lds[nn][c] = nf4[(n0 + nn) * C_DIM + c];
    }
    __syncthreads();

    const int d     = t & 127;
    const int half  = t >> 7;
    const int nbase = half * 4;

    const float* wsc0p[4];
    const float* wsc1p[4];
#pragma unroll
    for (int k = 0; k < 4; ++k) {
        int sp = specie[n0 + nbase + k];
        wsc0p[k] = Wsc0 + sp * C_DIM * C_DIM + d;
        wsc1p[k] = Wsc1 + sp * C_DIM * C_DIM + d;
    }
    const float* wp0 = Wpre0 + d;
    const float* wp1 = Wpre1 + d;

    float accS[4][4] = {};
    float accP[4][4] = {};

    for (int c = 0; c < C_DIM; ++c) {
        const float w_pre0 = wp0[c * C_DIM];
        const float w_pre1 = wp1[c * C_DIM];
#pragma unroll
        for (int k = 0; k < 4; ++k) {
            const float4 f  = in_lds[nbase + k][c];
            const float ws0 = wsc0p[k][c * C_DIM];
            const float ws1 = wsc1p[k][c * C_DIM];
            accS[k][0] += f.x * ws0;
            accS[k][1] += f.y * ws1;
            accS[k][2] += f.z * ws1;
            accS[k][3] += f.w * ws1;
            accP[k][0] += f.x * w_pre0;
            accP[k][1] += f.y * w_pre1;
            accP[k][2] += f.z * w_pre1;
            accP[k][3] += f.w * w_pre1;
        }
    }

    float4* sc4 = (float4*)out_sc;
    float4* sv4 = (float4*)sv;
#pragma unroll
    for (int k = 0; k < 4; ++k) {
        const int n = n0 + nbase + k;
        float4 o = {accS[k][0] * INV_C, accS[k][1] * INV_C,
                    accS[k][2] * INV_C, accS[k][3] * INV_C};
        sc4[n * C_DIM + d] = o;
        float4 p = {accP[k][0] * INV_C, accP[k][1] * INV_C,
                    accP[k][2] * INV_C, accP[k][3] * INV_C};
        sv4[n * C_DIM + d] = p;
    }
}

// ---------------------------------------------------------------------------
// Kernel B1: edge MLP  mix[e][0..3] = (silu(silu(ef@W1/sqrt8)@W2*.125)@W3)*.125
// One wave handles 8 edges; lane j owns hidden unit j.
// ---------------------------------------------------------------------------
__global__ __launch_bounds__(256) void edge_mlp_kernel(
    const float* __restrict__ edge_feats,   // [E][8]
    const float* __restrict__ W1,           // [8][64]
    const float* __restrict__ W2,           // [64][64]
    const float* __restrict__ W3,           // [64][4]
    float* __restrict__ mix)                // [E][4]
{
    __shared__ float h_lds[4][8][64];
    __shared__ float ef_lds[4][8][8];

    const int wave = threadIdx.x >> 6;
    const int lane = threadIdx.x & 63;
    const int base = (blockIdx.x * 4 + wave) * 8;   // first of 8 edges

    ef_lds[wave][lane >> 3][lane & 7] = edge_feats[base * 8 + lane];
    __syncthreads();

    // layer 1: h1[e][lane]
    float acc1[8] = {};
    for (int k = 0; k < 8; ++k) {
        const float w = W1[k * 64 + lane];
#pragma unroll
        for (int e = 0; e < 8; ++e) acc1[e] += ef_lds[wave][e][k] * w;
    }
#pragma unroll
    for (int e = 0; e < 8; ++e) {
        h_lds[wave][e][lane] = silu(acc1[e] * F_INV_SQRT8);
    }
    __syncthreads();

    // layer 2: h2[e][lane]
    float acc2[8] = {};
    for (int k = 0; k < 64; ++k) {
        const float w = W2[k * 64 + lane];
#pragma unroll
        for (int e = 0; e < 8; ++e) acc2[e] += h_lds[wave][e][k] * w;
    }
    __syncthreads();
#pragma unroll
    for (int e = 0; e < 8; ++e) {
        h_lds[wave][e][lane] = silu(acc2[e] * 0.125f);
    }
    __syncthreads();

    // layer 3: 32 lanes, (edge, m) pairs
    if (lane < 32) {
        const int e = lane >> 2, m = lane & 3;
        float s = 0.0f;
        for (int k = 0; k < 64; ++k) s += h_lds[wave][e][k] * W3[k * 4 + m];
        mix[(base + e) * 4 + m] = s * 0.125f;
    }
}

// ---------------------------------------------------------------------------
// Kernel B2: per-(edge,channel) message + atomic scatter into agg[N][C][8].
// Thread t: edge = blk*2 + (t>>7), channel c = t&127.
// ---------------------------------------------------------------------------
__global__ __launch_bounds__(256) void edge_msg_kernel(
    const float* __restrict__ edge_attrs,   // [E][4]
    const int* __restrict__ senders,
    const int* __restrict__ receivers,
    const float* __restrict__ sv,           // [N][C][4]
    const float* __restrict__ mix,          // [E][4]
    float* __restrict__ agg)                // [N][C][8]
{
    const int t = threadIdx.x;
    const int e = blockIdx.x * 2 + (t >> 7);
    const int c = t & 127;

    const int snd = senders[e];
    const int rcv = receivers[e];
    const float a1 = edge_attrs[e * 4 + 1];
    const float a2 = edge_attrs[e * 4 + 2];
    const float a3 = edge_attrs[e * 4 + 3];
    const float4 mx = ((const float4*)mix)[e];
    const float4 f  = ((const float4*)sv)[snd * C_DIM + c];

    const float s_e = f.x;
    const float dot = (f.y * a1 + f.z * a2 + f.w * a3) * F_INV_SQRT3;

    float* ap = agg + ((size_t)rcv * (C_DIM * 8) + c * 8);
    atomicAdd(ap + 0, s_e * mx.x);
    atomicAdd(ap + 1, dot * mx.y);
    atomicAdd(ap + 2, f.y * mx.z);
    atomicAdd(ap + 3, f.z * mx.z);
    atomicAdd(ap + 4, f.w * mx.z);
    atomicAdd(ap + 5, s_e * a1 * mx.w);
    atomicAdd(ap + 6, s_e * a2 * mx.w);
    atomicAdd(ap + 7, s_e * a3 * mx.w);
}

// ---------------------------------------------------------------------------
// Kernel C: per-node post transforms from agg.
//   o_s[n,d]   = sum_{c,m} agg[n,c,m]       * W_post0[c,m,d] * inv2c
//   o_v[n,d,i] = sum_{c,m} agg[n,c,2+m*3+i] * W_post1[c,m,d] * inv2c
// 8 nodes per block (agg tile staged in LDS, /16 applied on load).
// ---------------------------------------------------------------------------
__global__ __launch_bounds__(256) void node_post_kernel(
    const float* __restrict__ agg,          // [N][C][8]
    const float* __restrict__ Wpost0,       // [C][2][C]
    const float* __restrict__ Wpost1,
    float* __restrict__ out)                // [N][C][4] (first output)
{
    __shared__ float agg_lds[8][C_DIM][8];  // 32 KiB
    const int n0 = blockIdx.x * 8;
    const int t  = threadIdx.x;

    const float4* a4 = (const float4*)(agg + (size_t)n0 * (C_DIM * 8));
    float4* l4 = (float4*)agg_lds;
    for (int idx = t; idx < 8 * C_DIM * 8 / 4; idx += 256) {
        float4 v = a4[idx];
        v.x *= F_INV_AVG; v.y *= F_INV_AVG; v.z *= F_INV_AVG; v.w *= F_INV_AVG;
        l4[idx] = v;
    }
    __syncthreads();

    const int d     = t & 127;
    const int half  = t >> 7;
    const int nbase = half * 4;

    float acc[4][4] = {};
    for (int c = 0; c < C_DIM; ++c) {
#pragma unroll
        for (int m = 0; m < 2; ++m) {
            const float w0 = Wpost0[(c * 2 + m) * C_DIM + d];
            const float w1 = Wpost1[(c * 2 + m) * C_DIM + d];
#pragma unroll
            for (int k = 0; k < 4; ++k) {
                const float* ag = agg_lds[nbase + k][c];
                acc[k][0] += ag[m] * w0;
                acc[k][1] += ag[2 + m * 3 + 0] * w1;
                acc[k][2] += ag[2 + m * 3 + 1] * w1;
                acc[k][3] += ag[2 + m * 3 + 2] * w1;
            }
        }
    }

    float4* o4 = (float4*)out;
#pragma unroll
    for (int k = 0; k < 4; ++k) {
        const int n = n0 + nbase + k;
        float4 o = {acc[k][0] * INV_2C, acc[k][1] * INV_2C,
                    acc[k][2] * INV_2C, acc[k][3] * INV_2C};
        o4[n * C_DIM + d] = o;
    }
}

// ---------------------------------------------------------------------------
extern "C" void kernel_launch(void* const* d_in, const int* in_sizes, int n_in,
                              void* d_out, int out_size, void* d_ws, size_t ws_size,
                              hipStream_t stream)
{
    const int*   specie     = (const int*)d_in[0];
    const float* node_feats = (const float*)d_in[1];
    const float* edge_attrs = (const float*)d_in[2];
    const float* edge_feats = (const float*)d_in[3];
    const int*   senders    = (const int*)d_in[4];
    const int*   receivers  = (const int*)d_in[5];
    const float* Wsc0  = (const float*)d_in[6];
    const float* Wsc1  = (const float*)d_in[7];
    const float* Wpre0 = (const float*)d_in[8];
    const float* Wpre1 = (const float*)d_in[9];
    const float* Wm1   = (const float*)d_in[10];
    const float* Wm2   = (const float*)d_in[11];
    const float* Wm3   = (const float*)d_in[12];
    const float* Wp0   = (const float*)d_in[13];
    const float* Wp1   = (const float*)d_in[14];

    float* out_node = (float*)d_out;                           // [N][C][4]
    float* out_sc   = out_node + (size_t)N_NODES * C_DIM * 4;  // [N][C][4]

    // workspace layout: sv (32MB) | mix (4MB) | agg (64MB) = 100MB
    float* sv  = (float*)d_ws;
    float* mix = sv + (size_t)N_NODES * C_DIM * 4;
    float* agg = mix + (size_t)E_EDGES * 4;

    hipMemsetAsync(agg, 0, (size_t)N_NODES * C_DIM * 8 * sizeof(float), stream);

    node_pre_kernel<<<N_NODES / 8, 256, 0, stream>>>(
        specie, node_feats, Wsc0, Wsc1, Wpre0, Wpre1, out_sc, sv);

    edge_mlp_kernel<<<E_EDGES / 32, 256, 0, stream>>>(
        edge_feats, Wm1, Wm2, Wm3, mix);

    edge_msg_kernel<<<E_EDGES / 2, 256, 0, stream>>>(
        edge_attrs, senders, receivers, sv, mix, agg);

    node_post_kernel<<<N_NODES / 8, 256, 0, stream>>>(
        agg, Wp0, Wp1, out_node);
}

// Round 2
// 436.573 us; speedup vs baseline: 16.9966x; 16.9966x over previous
//
#include <hip/hip_runtime.h>

// Problem constants
#define N_NODES 16384
#define C_DIM   128
#define E_EDGES 262144
#define S_SPEC  10
#define CHUNK   256

__device__ __constant__ const float INV_C  = 0.08838834764831845f;  // 1/sqrt(128)
__device__ __constant__ const float INV_2C = 0.0625f;               // 1/sqrt(256)
#define F_INV_SQRT3 0.5773502691896258f
#define F_INV_SQRT8 0.35355339059327373f
#define F_INV_AVG   0.0625f   // 1/16 neighbors

__device__ __forceinline__ float silu(float x) {
    return x / (1.0f + __expf(-x));
}

// ---------------------------------------------------------------------------
// CSR build: histogram -> scan -> scatter permutation
// ---------------------------------------------------------------------------
__global__ __launch_bounds__(256) void hist_kernel(
    const int* __restrict__ receivers, int* __restrict__ cnt)
{
    const int e = blockIdx.x * 256 + threadIdx.x;
    atomicAdd(&cnt[receivers[e]], 1);
}

// 16384 = 256 threads x 64 elems each; single workgroup.
__global__ __launch_bounds__(256) void scan16k_kernel(
    const int* __restrict__ cnt, int* __restrict__ start)
{
    __shared__ int sums[256];
    const int t = threadIdx.x;
    int s = 0;
    for (int i = 0; i < 64; ++i) s += cnt[t * 64 + i];
    sums[t] = s;
    __syncthreads();
    if (t == 0) {
        int a = 0;
        for (int i = 0; i < 256; ++i) { int v = sums[i]; sums[i] = a; a += v; }
    }
    __syncthreads();
    int a = sums[t];
    for (int i = 0; i < 64; ++i) {
        int v = cnt[t * 64 + i];
        start[t * 64 + i] = a;
        a += v;
    }
    if (t == 255) start[N_NODES] = a;
}

__global__ __launch_bounds__(256) void scatter_kernel(
    const int* __restrict__ receivers, int* __restrict__ cursor,
    int* __restrict__ perm)
{
    const int e = blockIdx.x * 256 + threadIdx.x;
    const int pos = atomicAdd(&cursor[receivers[e]], 1);
    perm[pos] = e;
}

// ---------------------------------------------------------------------------
// Kernel A: per-node "pre" transforms (unchanged from round 1).
// ---------------------------------------------------------------------------
__global__ __launch_bounds__(256) void node_pre_kernel(
    const int* __restrict__ specie,
    const float* __restrict__ node_feats,   // [N][C][4]
    const float* __restrict__ Wsc0,         // [S][C][C]
    const float* __restrict__ Wsc1,
    const float* __restrict__ Wpre0,        // [C][C]
    const float* __restrict__ Wpre1,
    float* __restrict__ out_sc,             // [N][C][4] (second output)
    float* __restrict__ sv)                 // [N][C][4] workspace
{
    __shared__ float4 in_lds[8][C_DIM];
    const int n0 = blockIdx.x * 8;
    const int t  = threadIdx.x;

    const float4* nf4 = (const float4*)node_feats;
    for (int idx = t; idx < 8 * C_DIM; idx += 256) {
        int nn = idx >> 7, c = idx & 127;
        in_lds[nn][c] = nf4[(n0 + nn) * C_DIM + c];
    }
    __syncthreads();

    const int d     = t & 127;
    const int half  = t >> 7;
    const int nbase = half * 4;

    const float* wsc0p[4];
    const float* wsc1p[4];
#pragma unroll
    for (int k = 0; k < 4; ++k) {
        int sp = specie[n0 + nbase + k];
        wsc0p[k] = Wsc0 + sp * C_DIM * C_DIM + d;
        wsc1p[k] = Wsc1 + sp * C_DIM * C_DIM + d;
    }
    const float* wp0 = Wpre0 + d;
    const float* wp1 = Wpre1 + d;

    float accS[4][4] = {};
    float accP[4][4] = {};

    for (int c = 0; c < C_DIM; ++c) {
        const float w_pre0 = wp0[c * C_DIM];
        const float w_pre1 = wp1[c * C_DIM];
#pragma unroll
        for (int k = 0; k < 4; ++k) {
            const float4 f  = in_lds[nbase + k][c];
            const float ws0 = wsc0p[k][c * C_DIM];
            const float ws1 = wsc1p[k][c * C_DIM];
            accS[k][0] += f.x * ws0;
            accS[k][1] += f.y * ws1;
            accS[k][2] += f.z * ws1;
            accS[k][3] += f.w * ws1;
            accP[k][0] += f.x * w_pre0;
            accP[k][1] += f.y * w_pre1;
            accP[k][2] += f.z * w_pre1;
            accP[k][3] += f.w * w_pre1;
        }
    }

    float4* sc4 = (float4*)out_sc;
    float4* sv4 = (float4*)sv;
#pragma unroll
    for (int k = 0; k < 4; ++k) {
        const int n = n0 + nbase + k;
        float4 o = {accS[k][0] * INV_C, accS[k][1] * INV_C,
                    accS[k][2] * INV_C, accS[k][3] * INV_C};
        sc4[n * C_DIM + d] = o;
        float4 p = {accP[k][0] * INV_C, accP[k][1] * INV_C,
                    accP[k][2] * INV_C, accP[k][3] * INV_C};
        sv4[n * C_DIM + d] = p;
    }
}

// ---------------------------------------------------------------------------
// Kernel B: edge MLP -> per-edge 8-coefficient vector.
//   coef[e] = {mix0, mix1*a1/s3, mix1*a2/s3, mix1*a3/s3,
//              mix2, mix3*a1,    mix3*a2,    mix3*a3}
// ---------------------------------------------------------------------------
__global__ __launch_bounds__(256) void edge_mlp_kernel(
    const float* __restrict__ edge_feats,   // [E][8]
    const float* __restrict__ edge_attrs,   // [E][4]
    const float* __restrict__ W1,           // [8][64]
    const float* __restrict__ W2,           // [64][64]
    const float* __restrict__ W3,           // [64][4]
    float* __restrict__ coef)               // [E][8]
{
    __shared__ float h_lds[4][8][64];
    __shared__ float ef_lds[4][8][8];
    __shared__ float mix_lds[4][8][4];

    const int wave = threadIdx.x >> 6;
    const int lane = threadIdx.x & 63;
    const int base = (blockIdx.x * 4 + wave) * 8;   // first of 8 edges

    ef_lds[wave][lane >> 3][lane & 7] = edge_feats[base * 8 + lane];
    __syncthreads();

    float acc1[8] = {};
    for (int k = 0; k < 8; ++k) {
        const float w = W1[k * 64 + lane];
#pragma unroll
        for (int e = 0; e < 8; ++e) acc1[e] += ef_lds[wave][e][k] * w;
    }
#pragma unroll
    for (int e = 0; e < 8; ++e) h_lds[wave][e][lane] = silu(acc1[e] * F_INV_SQRT8);
    __syncthreads();

    float acc2[8] = {};
    for (int k = 0; k < 64; ++k) {
        const float w = W2[k * 64 + lane];
#pragma unroll
        for (int e = 0; e < 8; ++e) acc2[e] += h_lds[wave][e][k] * w;
    }
    __syncthreads();
#pragma unroll
    for (int e = 0; e < 8; ++e) h_lds[wave][e][lane] = silu(acc2[e] * 0.125f);
    __syncthreads();

    if (lane < 32) {
        const int e = lane >> 2, m = lane & 3;
        float s = 0.0f;
        for (int k = 0; k < 64; ++k) s += h_lds[wave][e][k] * W3[k * 4 + m];
        mix_lds[wave][e][m] = s * 0.125f;
    }
    __syncthreads();

    const int e2 = lane >> 3, j = lane & 7;
    const float* mx = mix_lds[wave][e2];
    float v;
    if (j == 0)      v = mx[0];
    else if (j <= 3) v = mx[1] * edge_attrs[(base + e2) * 4 + j] * F_INV_SQRT3;
    else if (j == 4) v = mx[2];
    else             v = mx[3] * edge_attrs[(base + e2) * 4 + (j - 4)];
    coef[(base + e2) * 8 + j] = v;
}

// ---------------------------------------------------------------------------
// Kernel C: fused CSR-gather aggregation + post GEMV. 8 nodes per block.
// Thread t: c = t&127, half = t>>7; each thread owns 4 nodes' channel c.
// Edge scalars for the block's contiguous CSR range staged in LDS.
// ---------------------------------------------------------------------------
__global__ __launch_bounds__(256) void agg_post_kernel(
    const int* __restrict__ start,          // [N+1]
    const int* __restrict__ perm,           // [E]
    const int* __restrict__ senders,
    const float* __restrict__ coef,         // [E][8]
    const float* __restrict__ sv,           // [N][C][4]
    const float* __restrict__ Wpost0,       // [C][2][C]
    const float* __restrict__ Wpost1,
    float* __restrict__ out)                // [N][C][4] (first output)
{
    __shared__ float agg_lds[8][C_DIM][9];  // padded: conflict-free writes
    __shared__ int   se_lds[CHUNK];
    __shared__ float sc_lds[CHUNK][8];

    const int n0   = blockIdx.x * 8;
    const int t    = threadIdx.x;
    const int c    = t & 127;
    const int half = t >> 7;

    int nbeg[4], nend[4];
#pragma unroll
    for (int k = 0; k < 4; ++k) {
        nbeg[k] = start[n0 + half * 4 + k];
        nend[k] = start[n0 + half * 4 + k + 1];
    }

    const int blk_beg = start[n0];
    const int blk_end = start[n0 + 8];
    const float4* sv4   = (const float4*)sv;
    const float4* coef4 = (const float4*)coef;

    float acc[4][8] = {};

    for (int cb = blk_beg; cb < blk_end; cb += CHUNK) {
        const int cn = min(CHUNK, blk_end - cb);
        __syncthreads();                     // protect LDS reuse across chunks
        for (int j = t; j < cn; j += 256) {
            const int e = perm[cb + j];
            se_lds[j] = senders[e];
            ((float4*)sc_lds[j])[0] = coef4[e * 2 + 0];
            ((float4*)sc_lds[j])[1] = coef4[e * 2 + 1];
        }
        __syncthreads();
#pragma unroll
        for (int k = 0; k < 4; ++k) {
            const int lo = max(nbeg[k], cb);
            const int hi = min(nend[k], cb + cn);
            for (int idx = lo; idx < hi; ++idx) {
                const int j = idx - cb;
                const int snd = se_lds[j];
                const float* kf = sc_lds[j];
                const float4 f = sv4[snd * C_DIM + c];
                acc[k][0] += f.x * kf[0];
                acc[k][1] += f.y * kf[1] + f.z * kf[2] + f.w * kf[3];
                acc[k][2] += f.y * kf[4];
                acc[k][3] += f.z * kf[4];
                acc[k][4] += f.w * kf[4];
                acc[k][5] += f.x * kf[5];
                acc[k][6] += f.x * kf[6];
                acc[k][7] += f.x * kf[7];
            }
        }
    }

#pragma unroll
    for (int k = 0; k < 4; ++k)
#pragma unroll
        for (int m = 0; m < 8; ++m)
            agg_lds[half * 4 + k][c][m] = acc[k][m] * F_INV_AVG;
    __syncthreads();

    // post GEMV
    const int d     = c;
    const int nbase = half * 4;
    float o[4][4] = {};
    for (int cc = 0; cc < C_DIM; ++cc) {
#pragma unroll
        for (int m = 0; m < 2; ++m) {
            const float w0 = Wpost0[(cc * 2 + m) * C_DIM + d];
            const float w1 = Wpost1[(cc * 2 + m) * C_DIM + d];
#pragma unroll
            for (int k = 0; k < 4; ++k) {
                const float* ag = agg_lds[nbase + k][cc];
                o[k][0] += ag[m] * w0;
                o[k][1] += ag[2 + m * 3 + 0] * w1;
                o[k][2] += ag[2 + m * 3 + 1] * w1;
                o[k][3] += ag[2 + m * 3 + 2] * w1;
            }
        }
    }

    float4* o4 = (float4*)out;
#pragma unroll
    for (int k = 0; k < 4; ++k) {
        const int n = n0 + nbase + k;
        float4 ov = {o[k][0] * INV_2C, o[k][1] * INV_2C,
                     o[k][2] * INV_2C, o[k][3] * INV_2C};
        o4[n * C_DIM + d] = ov;
    }
}

// ---------------------------------------------------------------------------
extern "C" void kernel_launch(void* const* d_in, const int* in_sizes, int n_in,
                              void* d_out, int out_size, void* d_ws, size_t ws_size,
                              hipStream_t stream)
{
    const int*   specie     = (const int*)d_in[0];
    const float* node_feats = (const float*)d_in[1];
    const float* edge_attrs = (const float*)d_in[2];
    const float* edge_feats = (const float*)d_in[3];
    const int*   senders    = (const int*)d_in[4];
    const int*   receivers  = (const int*)d_in[5];
    const float* Wsc0  = (const float*)d_in[6];
    const float* Wsc1  = (const float*)d_in[7];
    const float* Wpre0 = (const float*)d_in[8];
    const float* Wpre1 = (const float*)d_in[9];
    const float* Wm1   = (const float*)d_in[10];
    const float* Wm2   = (const float*)d_in[11];
    const float* Wm3   = (const float*)d_in[12];
    const float* Wp0   = (const float*)d_in[13];
    const float* Wp1   = (const float*)d_in[14];

    float* out_node = (float*)d_out;                           // [N][C][4]
    float* out_sc   = out_node + (size_t)N_NODES * C_DIM * 4;  // [N][C][4]

    // workspace: sv 32MB | coef 8MB | counts | start | cursor | perm  (~43MB)
    float* sv     = (float*)d_ws;
    float* coef   = sv + (size_t)N_NODES * C_DIM * 4;
    int*   counts = (int*)(coef + (size_t)E_EDGES * 8);
    int*   start  = counts + N_NODES;
    int*   cursor = start + (N_NODES + 1);
    int*   perm   = cursor + N_NODES;

    // --- CSR build ---
    hipMemsetAsync(counts, 0, N_NODES * sizeof(int), stream);
    hist_kernel<<<E_EDGES / 256, 256, 0, stream>>>(receivers, counts);
    scan16k_kernel<<<1, 256, 0, stream>>>(counts, start);
    hipMemcpyAsync(cursor, start, N_NODES * sizeof(int),
                   hipMemcpyDeviceToDevice, stream);
    scatter_kernel<<<E_EDGES / 256, 256, 0, stream>>>(receivers, cursor, perm);

    // --- node pre transforms (also writes output 2: sc) ---
    node_pre_kernel<<<N_NODES / 8, 256, 0, stream>>>(
        specie, node_feats, Wsc0, Wsc1, Wpre0, Wpre1, out_sc, sv);

    // --- edge MLP -> coefficients ---
    edge_mlp_kernel<<<E_EDGES / 32, 256, 0, stream>>>(
        edge_feats, edge_attrs, Wm1, Wm2, Wm3, coef);

    // --- fused gather-aggregate + post GEMV (output 1) ---
    agg_post_kernel<<<N_NODES / 8, 256, 0, stream>>>(
        start, perm, senders, coef, sv, Wp0, Wp1, out_node);
}

// Round 3
// 426.421 us; speedup vs baseline: 17.4013x; 1.0238x over previous
//
#include <hip/hip_runtime.h>
#include <hip/hip_bf16.h>

// Problem constants
#define N_NODES 16384
#define C_DIM   128
#define E_EDGES 262144
#define S_SPEC  10
#define CHUNK   256

__device__ __constant__ const float INV_C  = 0.08838834764831845f;  // 1/sqrt(128)
__device__ __constant__ const float INV_2C = 0.0625f;               // 1/sqrt(256)
#define F_INV_SQRT3 0.5773502691896258f
#define F_INV_SQRT8 0.35355339059327373f
#define F_INV_AVG   0.0625f   // 1/16 neighbors

__device__ __forceinline__ float silu(float x) {
    return x / (1.0f + __expf(-x));
}

__device__ __forceinline__ unsigned short f2bf(float x) {
    __hip_bfloat16 h = __float2bfloat16(x);
    return *reinterpret_cast<unsigned short*>(&h);
}

__device__ __forceinline__ float bf2f(unsigned short u) {
    return __uint_as_float(((unsigned int)u) << 16);
}

// ---------------------------------------------------------------------------
// CSR build (receiver -> edge list): histogram -> scan -> scatter perm
// ---------------------------------------------------------------------------
__global__ __launch_bounds__(256) void hist_kernel(
    const int* __restrict__ receivers, int* __restrict__ cnt)
{
    const int e = blockIdx.x * 256 + threadIdx.x;
    atomicAdd(&cnt[receivers[e]], 1);
}

__global__ __launch_bounds__(256) void scan16k_kernel(
    const int* __restrict__ cnt, int* __restrict__ start)
{
    __shared__ int sums[256];
    const int t = threadIdx.x;
    int s = 0;
    for (int i = 0; i < 64; ++i) s += cnt[t * 64 + i];
    sums[t] = s;
    __syncthreads();
    if (t == 0) {
        int a = 0;
        for (int i = 0; i < 256; ++i) { int v = sums[i]; sums[i] = a; a += v; }
    }
    __syncthreads();
    int a = sums[t];
    for (int i = 0; i < 64; ++i) {
        int v = cnt[t * 64 + i];
        start[t * 64 + i] = a;
        a += v;
    }
    if (t == 255) start[N_NODES] = a;
}

__global__ __launch_bounds__(256) void scatter_kernel(
    const int* __restrict__ receivers, int* __restrict__ cursor,
    int* __restrict__ perm)
{
    const int e = blockIdx.x * 256 + threadIdx.x;
    const int pos = atomicAdd(&cursor[receivers[e]], 1);
    perm[pos] = e;
}

// ---------------------------------------------------------------------------
// Species sort: 10-bin histogram -> scan -> scatter node_perm
// ---------------------------------------------------------------------------
__global__ __launch_bounds__(256) void spec_hist_kernel(
    const int* __restrict__ specie, int* __restrict__ scnt)
{
    __shared__ int h[S_SPEC];
    const int t = threadIdx.x;
    if (t < S_SPEC) h[t] = 0;
    __syncthreads();
    atomicAdd(&h[specie[blockIdx.x * 256 + t]], 1);
    __syncthreads();
    if (t < S_SPEC) atomicAdd(&scnt[t], h[t]);
}

__global__ void spec_scan_kernel(
    const int* __restrict__ scnt, int* __restrict__ scur)
{
    if (threadIdx.x == 0) {
        int a = 0;
        for (int i = 0; i < S_SPEC; ++i) { scur[i] = a; a += scnt[i]; }
    }
}

__global__ __launch_bounds__(256) void spec_scatter_kernel(
    const int* __restrict__ specie, int* __restrict__ scur,
    int* __restrict__ node_perm)
{
    const int n = blockIdx.x * 256 + threadIdx.x;
    const int pos = atomicAdd(&scur[specie[n]], 1);
    node_perm[pos] = n;
}

// ---------------------------------------------------------------------------
// Kernel A: per-node "pre" transforms, species-sorted node order.
// Writes out_sc (f32, output 2) and sv (bf16 workspace for the gather).
// ---------------------------------------------------------------------------
__global__ __launch_bounds__(256) void node_pre_kernel(
    const int* __restrict__ node_perm,
    const int* __restrict__ specie,
    const float* __restrict__ node_feats,   // [N][C][4]
    const float* __restrict__ Wsc0,         // [S][C][C]
    const float* __restrict__ Wsc1,
    const float* __restrict__ Wpre0,        // [C][C]
    const float* __restrict__ Wpre1,
    float* __restrict__ out_sc,             // [N][C][4] (second output)
    ushort4* __restrict__ sv_bf)            // [N][C] bf16x4 workspace
{
    __shared__ float4 in_lds[8][C_DIM];
    __shared__ int nid[8];
    const int n0 = blockIdx.x * 8;
    const int t  = threadIdx.x;

    if (t < 8) nid[t] = node_perm[n0 + t];
    __syncthreads();

    const float4* nf4 = (const float4*)node_feats;
    for (int idx = t; idx < 8 * C_DIM; idx += 256) {
        int nn = idx >> 7, c = idx & 127;
        in_lds[nn][c] = nf4[nid[nn] * C_DIM + c];
    }
    __syncthreads();

    const int d     = t & 127;
    const int half  = t >> 7;
    const int nbase = half * 4;

    int sp[4];
#pragma unroll
    for (int k = 0; k < 4; ++k) sp[k] = specie[nid[nbase + k]];

    const float* wp0 = Wpre0 + d;
    const float* wp1 = Wpre1 + d;

    float accS[4][4] = {};
    float accP[4][4] = {};

    const bool same = (sp[0] == sp[1]) & (sp[1] == sp[2]) & (sp[2] == sp[3]);
    if (same) {
        // fast path: one weight stream for all 4 nodes (wave-uniform branch)
        const float* w0 = Wsc0 + sp[0] * C_DIM * C_DIM + d;
        const float* w1 = Wsc1 + sp[0] * C_DIM * C_DIM + d;
        for (int c = 0; c < C_DIM; ++c) {
            const float ws0    = w0[c * C_DIM];
            const float ws1    = w1[c * C_DIM];
            const float w_pre0 = wp0[c * C_DIM];
            const float w_pre1 = wp1[c * C_DIM];
#pragma unroll
            for (int k = 0; k < 4; ++k) {
                const float4 f = in_lds[nbase + k][c];
                accS[k][0] += f.x * ws0;
                accS[k][1] += f.y * ws1;
                accS[k][2] += f.z * ws1;
                accS[k][3] += f.w * ws1;
                accP[k][0] += f.x * w_pre0;
                accP[k][1] += f.y * w_pre1;
                accP[k][2] += f.z * w_pre1;
                accP[k][3] += f.w * w_pre1;
            }
        }
    } else {
        const float* wsc0p[4];
        const float* wsc1p[4];
#pragma unroll
        for (int k = 0; k < 4; ++k) {
            wsc0p[k] = Wsc0 + sp[k] * C_DIM * C_DIM + d;
            wsc1p[k] = Wsc1 + sp[k] * C_DIM * C_DIM + d;
        }
        for (int c = 0; c < C_DIM; ++c) {
            const float w_pre0 = wp0[c * C_DIM];
            const float w_pre1 = wp1[c * C_DIM];
#pragma unroll
            for (int k = 0; k < 4; ++k) {
                const float4 f  = in_lds[nbase + k][c];
                const float ws0 = wsc0p[k][c * C_DIM];
                const float ws1 = wsc1p[k][c * C_DIM];
                accS[k][0] += f.x * ws0;
                accS[k][1] += f.y * ws1;
                accS[k][2] += f.z * ws1;
                accS[k][3] += f.w * ws1;
                accP[k][0] += f.x * w_pre0;
                accP[k][1] += f.y * w_pre1;
                accP[k][2] += f.z * w_pre1;
                accP[k][3] += f.w * w_pre1;
            }
        }
    }

    float4* sc4 = (float4*)out_sc;
#pragma unroll
    for (int k = 0; k < 4; ++k) {
        const int n = nid[nbase + k];
        float4 o = {accS[k][0] * INV_C, accS[k][1] * INV_C,
                    accS[k][2] * INV_C, accS[k][3] * INV_C};
        sc4[n * C_DIM + d] = o;
        ushort4 p = {f2bf(accP[k][0] * INV_C), f2bf(accP[k][1] * INV_C),
                     f2bf(accP[k][2] * INV_C), f2bf(accP[k][3] * INV_C)};
        sv_bf[n * C_DIM + d] = p;
    }
}

// ---------------------------------------------------------------------------
// Kernel B: edge MLP -> per-edge 8-coefficient vector.
// ---------------------------------------------------------------------------
__global__ __launch_bounds__(256) void edge_mlp_kernel(
    const float* __restrict__ edge_feats,   // [E][8]
    const float* __restrict__ edge_attrs,   // [E][4]
    const float* __restrict__ W1,           // [8][64]
    const float* __restrict__ W2,           // [64][64]
    const float* __restrict__ W3,           // [64][4]
    float* __restrict__ coef)               // [E][8]
{
    __shared__ float h_lds[4][8][64];
    __shared__ float ef_lds[4][8][8];
    __shared__ float mix_lds[4][8][4];

    const int wave = threadIdx.x >> 6;
    const int lane = threadIdx.x & 63;
    const int base = (blockIdx.x * 4 + wave) * 8;

    ef_lds[wave][lane >> 3][lane & 7] = edge_feats[base * 8 + lane];
    __syncthreads();

    float acc1[8] = {};
    for (int k = 0; k < 8; ++k) {
        const float w = W1[k * 64 + lane];
#pragma unroll
        for (int e = 0; e < 8; ++e) acc1[e] += ef_lds[wave][e][k] * w;
    }
#pragma unroll
    for (int e = 0; e < 8; ++e) h_lds[wave][e][lane] = silu(acc1[e] * F_INV_SQRT8);
    __syncthreads();

    float acc2[8] = {};
    for (int k = 0; k < 64; ++k) {
        const float w = W2[k * 64 + lane];
#pragma unroll
        for (int e = 0; e < 8; ++e) acc2[e] += h_lds[wave][e][k] * w;
    }
    __syncthreads();
#pragma unroll
    for (int e = 0; e < 8; ++e) h_lds[wave][e][lane] = silu(acc2[e] * 0.125f);
    __syncthreads();

    if (lane < 32) {
        const int e = lane >> 2, m = lane & 3;
        float s = 0.0f;
        for (int k = 0; k < 64; ++k) s += h_lds[wave][e][k] * W3[k * 4 + m];
        mix_lds[wave][e][m] = s * 0.125f;
    }
    __syncthreads();

    const int e2 = lane >> 3, j = lane & 7;
    const float* mx = mix_lds[wave][e2];
    float v;
    if (j == 0)      v = mx[0];
    else if (j <= 3) v = mx[1] * edge_attrs[(base + e2) * 4 + j] * F_INV_SQRT3;
    else if (j == 4) v = mx[2];
    else             v = mx[3] * edge_attrs[(base + e2) * 4 + (j - 4)];
    coef[(base + e2) * 8 + j] = v;
}

// ---------------------------------------------------------------------------
// Kernel C1: CSR-gather aggregation only (small LDS -> high occupancy).
// Writes agg[N][C][8] (raw sums; /16 applied in post kernel).
// ---------------------------------------------------------------------------
__global__ __launch_bounds__(256) void agg_kernel(
    const int* __restrict__ start,          // [N+1]
    const int* __restrict__ perm,           // [E]
    const int* __restrict__ senders,
    const float* __restrict__ coef,         // [E][8]
    const ushort4* __restrict__ sv_bf,      // [N][C] bf16x4
    float* __restrict__ agg)                // [N][C][8]
{
    __shared__ int   se_lds[CHUNK];
    __shared__ float sc_lds[CHUNK][8];

    const int n0   = blockIdx.x * 8;
    const int t    = threadIdx.x;
    const int c    = t & 127;
    const int half = t >> 7;

    int nbeg[4], nend[4];
#pragma unroll
    for (int k = 0; k < 4; ++k) {
        nbeg[k] = start[n0 + half * 4 + k];
        nend[k] = start[n0 + half * 4 + k + 1];
    }

    const int blk_beg = start[n0];
    const int blk_end = start[n0 + 8];
    const float4* coef4 = (const float4*)coef;

    float acc[4][8] = {};

    for (int cb = blk_beg; cb < blk_end; cb += CHUNK) {
        const int cn = min(CHUNK, blk_end - cb);
        __syncthreads();
        for (int j = t; j < cn; j += 256) {
            const int e = perm[cb + j];
            se_lds[j] = senders[e];
            ((float4*)sc_lds[j])[0] = coef4[e * 2 + 0];
            ((float4*)sc_lds[j])[1] = coef4[e * 2 + 1];
        }
        __syncthreads();

#pragma unroll
        for (int k = 0; k < 4; ++k) {
            const int lo = max(nbeg[k], cb);
            const int hi = min(nend[k], cb + cn);
            int idx = lo;
            for (; idx + 2 <= hi; idx += 2) {
                const int j0 = idx - cb, j1 = j0 + 1;
                const int snd0 = se_lds[j0];
                const int snd1 = se_lds[j1];
                const ushort4 u0 = sv_bf[snd0 * C_DIM + c];
                const ushort4 u1 = sv_bf[snd1 * C_DIM + c];
                const float* kf0 = sc_lds[j0];
                const float* kf1 = sc_lds[j1];
                const float x0 = bf2f(u0.x), y0 = bf2f(u0.y),
                            z0 = bf2f(u0.z), w0 = bf2f(u0.w);
                const float x1 = bf2f(u1.x), y1 = bf2f(u1.y),
                            z1 = bf2f(u1.z), w1 = bf2f(u1.w);
                acc[k][0] += x0 * kf0[0];
                acc[k][1] += y0 * kf0[1] + z0 * kf0[2] + w0 * kf0[3];
                acc[k][2] += y0 * kf0[4];
                acc[k][3] += z0 * kf0[4];
                acc[k][4] += w0 * kf0[4];
                acc[k][5] += x0 * kf0[5];
                acc[k][6] += x0 * kf0[6];
                acc[k][7] += x0 * kf0[7];
                acc[k][0] += x1 * kf1[0];
                acc[k][1] += y1 * kf1[1] + z1 * kf1[2] + w1 * kf1[3];
                acc[k][2] += y1 * kf1[4];
                acc[k][3] += z1 * kf1[4];
                acc[k][4] += w1 * kf1[4];
                acc[k][5] += x1 * kf1[5];
                acc[k][6] += x1 * kf1[6];
                acc[k][7] += x1 * kf1[7];
            }
            if (idx < hi) {
                const int j = idx - cb;
                const int snd = se_lds[j];
                const ushort4 u = sv_bf[snd * C_DIM + c];
                const float* kf = sc_lds[j];
                const float x = bf2f(u.x), y = bf2f(u.y),
                            z = bf2f(u.z), w = bf2f(u.w);
                acc[k][0] += x * kf[0];
                acc[k][1] += y * kf[1] + z * kf[2] + w * kf[3];
                acc[k][2] += y * kf[4];
                acc[k][3] += z * kf[4];
                acc[k][4] += w * kf[4];
                acc[k][5] += x * kf[5];
                acc[k][6] += x * kf[6];
                acc[k][7] += x * kf[7];
            }
        }
    }

    float4* ag4 = (float4*)agg;
#pragma unroll
    for (int k = 0; k < 4; ++k) {
        const size_t base = ((size_t)(n0 + half * 4 + k) * C_DIM + c) * 2;
        ag4[base + 0] = make_float4(acc[k][0], acc[k][1], acc[k][2], acc[k][3]);
        ag4[base + 1] = make_float4(acc[k][4], acc[k][5], acc[k][6], acc[k][7]);
    }
}

// ---------------------------------------------------------------------------
// Kernel C2: per-node post GEMV from agg (round-1 structure).
// ---------------------------------------------------------------------------
__global__ __launch_bounds__(256) void node_post_kernel(
    const float* __restrict__ agg,          // [N][C][8]
    const float* __restrict__ Wpost0,       // [C][2][C]
    const float* __restrict__ Wpost1,
    float* __restrict__ out)                // [N][C][4] (first output)
{
    __shared__ float agg_lds[8][C_DIM][8];  // 32 KiB
    const int n0 = blockIdx.x * 8;
    const int t  = threadIdx.x;

    const float4* a4 = (const float4*)(agg + (size_t)n0 * (C_DIM * 8));
    float4* l4 = (float4*)agg_lds;
    for (int idx = t; idx < 8 * C_DIM * 8 / 4; idx += 256) {
        float4 v = a4[idx];
        v.x *= F_INV_AVG; v.y *= F_INV_AVG; v.z *= F_INV_AVG; v.w *= F_INV_AVG;
        l4[idx] = v;
    }
    __syncthreads();

    const int d     = t & 127;
    const int half  = t >> 7;
    const int nbase = half * 4;

    float acc[4][4] = {};
    for (int c = 0; c < C_DIM; ++c) {
#pragma unroll
        for (int m = 0; m < 2; ++m) {
            const float w0 = Wpost0[(c * 2 + m) * C_DIM + d];
            const float w1 = Wpost1[(c * 2 + m) * C_DIM + d];
#pragma unroll
            for (int k = 0; k < 4; ++k) {
                const float* ag = agg_lds[nbase + k][c];
                acc[k][0] += ag[m] * w0;
                acc[k][1] += ag[2 + m * 3 + 0] * w1;
                acc[k][2] += ag[2 + m * 3 + 1] * w1;
                acc[k][3] += ag[2 + m * 3 + 2] * w1;
            }
        }
    }

    float4* o4 = (float4*)out;
#pragma unroll
    for (int k = 0; k < 4; ++k) {
        const int n = n0 + nbase + k;
        float4 o = {acc[k][0] * INV_2C, acc[k][1] * INV_2C,
                    acc[k][2] * INV_2C, acc[k][3] * INV_2C};
        o4[n * C_DIM + d] = o;
    }
}

// ---------------------------------------------------------------------------
extern "C" void kernel_launch(void* const* d_in, const int* in_sizes, int n_in,
                              void* d_out, int out_size, void* d_ws, size_t ws_size,
                              hipStream_t stream)
{
    const int*   specie     = (const int*)d_in[0];
    const float* node_feats = (const float*)d_in[1];
    const float* edge_attrs = (const float*)d_in[2];
    const float* edge_feats = (const float*)d_in[3];
    const int*   senders    = (const int*)d_in[4];
    const int*   receivers  = (const int*)d_in[5];
    const float* Wsc0  = (const float*)d_in[6];
    const float* Wsc1  = (const float*)d_in[7];
    const float* Wpre0 = (const float*)d_in[8];
    const float* Wpre1 = (const float*)d_in[9];
    const float* Wm1   = (const float*)d_in[10];
    const float* Wm2   = (const float*)d_in[11];
    const float* Wm3   = (const float*)d_in[12];
    const float* Wp0   = (const float*)d_in[13];
    const float* Wp1   = (const float*)d_in[14];

    float* out_node = (float*)d_out;                           // [N][C][4]
    float* out_sc   = out_node + (size_t)N_NODES * C_DIM * 4;  // [N][C][4]

    // workspace layout
    char* ws = (char*)d_ws;
    ushort4* sv_bf = (ushort4*)ws;                                   // 16 MB
    float* agg  = (float*)(ws + (size_t)N_NODES * C_DIM * 8);        // 67 MB
    float* coef = agg + (size_t)N_NODES * C_DIM * 8;                 // 8 MB
    int* counts    = (int*)(coef + (size_t)E_EDGES * 8);
    int* start     = counts + N_NODES;
    int* cursor    = start + (N_NODES + 1);
    int* perm      = cursor + N_NODES;
    int* scnt      = perm + E_EDGES;
    int* scur      = scnt + S_SPEC;
    int* node_perm = scur + S_SPEC;

    // --- CSR build (receiver -> edges) ---
    hipMemsetAsync(counts, 0, N_NODES * sizeof(int), stream);
    hipMemsetAsync(scnt, 0, S_SPEC * sizeof(int), stream);
    hist_kernel<<<E_EDGES / 256, 256, 0, stream>>>(receivers, counts);
    scan16k_kernel<<<1, 256, 0, stream>>>(counts, start);
    hipMemcpyAsync(cursor, start, N_NODES * sizeof(int),
                   hipMemcpyDeviceToDevice, stream);
    scatter_kernel<<<E_EDGES / 256, 256, 0, stream>>>(receivers, cursor, perm);

    // --- species sort of nodes ---
    spec_hist_kernel<<<N_NODES / 256, 256, 0, stream>>>(specie, scnt);
    spec_scan_kernel<<<1, 64, 0, stream>>>(scnt, scur);
    spec_scatter_kernel<<<N_NODES / 256, 256, 0, stream>>>(specie, scur, node_perm);

    // --- node pre transforms (writes output 2: sc; sv as bf16) ---
    node_pre_kernel<<<N_NODES / 8, 256, 0, stream>>>(
        node_perm, specie, node_feats, Wsc0, Wsc1, Wpre0, Wpre1, out_sc, sv_bf);

    // --- edge MLP -> coefficients ---
    edge_mlp_kernel<<<E_EDGES / 32, 256, 0, stream>>>(
        edge_feats, edge_attrs, Wm1, Wm2, Wm3, coef);

    // --- gather-aggregate ---
    agg_kernel<<<N_NODES / 8, 256, 0, stream>>>(
        start, perm, senders, coef, sv_bf, agg);

    // --- post GEMV (output 1) ---
    node_post_kernel<<<N_NODES / 8, 256, 0, stream>>>(
        agg, Wp0, Wp1, out_node);
}

// Round 4
// 349.824 us; speedup vs baseline: 21.2114x; 1.2190x over previous
//
#include <hip/hip_runtime.h>
#include <hip/hip_bf16.h>

// Problem constants
#define N_NODES 16384
#define C_DIM   128
#define E_EDGES 262144
#define S_SPEC  10
#define CHUNK   256

__device__ __constant__ const float INV_C  = 0.08838834764831845f;  // 1/sqrt(128)
__device__ __constant__ const float INV_2C = 0.0625f;               // 1/sqrt(256)
#define F_INV_SQRT3 0.5773502691896258f
#define F_INV_SQRT8 0.35355339059327373f
#define F_INV_AVG   0.0625f   // 1/16 neighbors

typedef __attribute__((ext_vector_type(8))) short bf16x8;
typedef __attribute__((ext_vector_type(4))) float f32x4;

__device__ __forceinline__ float silu(float x) {
    return x / (1.0f + __expf(-x));
}

__device__ __forceinline__ unsigned short f2bf(float x) {
    __hip_bfloat16 h = __float2bfloat16(x);
    return *reinterpret_cast<unsigned short*>(&h);
}

__device__ __forceinline__ unsigned int pack2bf(float lo, float hi) {
    return (unsigned int)f2bf(lo) | ((unsigned int)f2bf(hi) << 16);
}

__device__ __forceinline__ float bf2f(unsigned short u) {
    return __uint_as_float(((unsigned int)u) << 16);
}

// ---------------------------------------------------------------------------
// CSR build (receiver -> edge list): histogram -> scan -> scatter perm
// ---------------------------------------------------------------------------
__global__ __launch_bounds__(256) void hist_kernel(
    const int* __restrict__ receivers, int* __restrict__ cnt)
{
    const int e = blockIdx.x * 256 + threadIdx.x;
    atomicAdd(&cnt[receivers[e]], 1);
}

__global__ __launch_bounds__(256) void scan16k_kernel(
    const int* __restrict__ cnt, int* __restrict__ start)
{
    __shared__ int sums[256];
    const int t = threadIdx.x;
    int s = 0;
    for (int i = 0; i < 64; ++i) s += cnt[t * 64 + i];
    sums[t] = s;
    __syncthreads();
    if (t == 0) {
        int a = 0;
        for (int i = 0; i < 256; ++i) { int v = sums[i]; sums[i] = a; a += v; }
    }
    __syncthreads();
    int a = sums[t];
    for (int i = 0; i < 64; ++i) {
        int v = cnt[t * 64 + i];
        start[t * 64 + i] = a;
        a += v;
    }
    if (t == 255) start[N_NODES] = a;
}

__global__ __launch_bounds__(256) void scatter_kernel(
    const int* __restrict__ receivers, int* __restrict__ cursor,
    int* __restrict__ perm)
{
    const int e = blockIdx.x * 256 + threadIdx.x;
    const int pos = atomicAdd(&cursor[receivers[e]], 1);
    perm[pos] = e;
}

// ---------------------------------------------------------------------------
// Species sort: 10-bin histogram -> scan -> scatter node_perm
// ---------------------------------------------------------------------------
__global__ __launch_bounds__(256) void spec_hist_kernel(
    const int* __restrict__ specie, int* __restrict__ scnt)
{
    __shared__ int h[S_SPEC];
    const int t = threadIdx.x;
    if (t < S_SPEC) h[t] = 0;
    __syncthreads();
    atomicAdd(&h[specie[blockIdx.x * 256 + t]], 1);
    __syncthreads();
    if (t < S_SPEC) atomicAdd(&scnt[t], h[t]);
}

__global__ void spec_scan_kernel(
    const int* __restrict__ scnt, int* __restrict__ scur)
{
    if (threadIdx.x == 0) {
        int a = 0;
        for (int i = 0; i < S_SPEC; ++i) { scur[i] = a; a += scnt[i]; }
    }
}

__global__ __launch_bounds__(256) void spec_scatter_kernel(
    const int* __restrict__ specie, int* __restrict__ scur,
    int* __restrict__ node_perm)
{
    const int n = blockIdx.x * 256 + threadIdx.x;
    const int pos = atomicAdd(&scur[specie[n]], 1);
    node_perm[pos] = n;
}

// ---------------------------------------------------------------------------
// Kernel A: per-node "pre" transforms, species-sorted node order.
// ---------------------------------------------------------------------------
__global__ __launch_bounds__(256) void node_pre_kernel(
    const int* __restrict__ node_perm,
    const int* __restrict__ specie,
    const float* __restrict__ node_feats,   // [N][C][4]
    const float* __restrict__ Wsc0,         // [S][C][C]
    const float* __restrict__ Wsc1,
    const float* __restrict__ Wpre0,        // [C][C]
    const float* __restrict__ Wpre1,
    float* __restrict__ out_sc,             // [N][C][4] (second output)
    ushort4* __restrict__ sv_bf)            // [N][C] bf16x4 workspace
{
    __shared__ float4 in_lds[8][C_DIM];
    __shared__ int nid[8];
    const int n0 = blockIdx.x * 8;
    const int t  = threadIdx.x;

    if (t < 8) nid[t] = node_perm[n0 + t];
    __syncthreads();

    const float4* nf4 = (const float4*)node_feats;
    for (int idx = t; idx < 8 * C_DIM; idx += 256) {
        int nn = idx >> 7, c = idx & 127;
        in_lds[nn][c] = nf4[nid[nn] * C_DIM + c];
    }
    __syncthreads();

    const int d     = t & 127;
    const int half  = t >> 7;
    const int nbase = half * 4;

    int sp[4];
#pragma unroll
    for (int k = 0; k < 4; ++k) sp[k] = specie[nid[nbase + k]];

    const float* wp0 = Wpre0 + d;
    const float* wp1 = Wpre1 + d;

    float accS[4][4] = {};
    float accP[4][4] = {};

    const bool same = (sp[0] == sp[1]) & (sp[1] == sp[2]) & (sp[2] == sp[3]);
    if (same) {
        const float* w0 = Wsc0 + sp[0] * C_DIM * C_DIM + d;
        const float* w1 = Wsc1 + sp[0] * C_DIM * C_DIM + d;
        for (int c = 0; c < C_DIM; ++c) {
            const float ws0    = w0[c * C_DIM];
            const float ws1    = w1[c * C_DIM];
            const float w_pre0 = wp0[c * C_DIM];
            const float w_pre1 = wp1[c * C_DIM];
#pragma unroll
            for (int k = 0; k < 4; ++k) {
                const float4 f = in_lds[nbase + k][c];
                accS[k][0] += f.x * ws0;
                accS[k][1] += f.y * ws1;
                accS[k][2] += f.z * ws1;
                accS[k][3] += f.w * ws1;
                accP[k][0] += f.x * w_pre0;
                accP[k][1] += f.y * w_pre1;
                accP[k][2] += f.z * w_pre1;
                accP[k][3] += f.w * w_pre1;
            }
        }
    } else {
        const float* wsc0p[4];
        const float* wsc1p[4];
#pragma unroll
        for (int k = 0; k < 4; ++k) {
            wsc0p[k] = Wsc0 + sp[k] * C_DIM * C_DIM + d;
            wsc1p[k] = Wsc1 + sp[k] * C_DIM * C_DIM + d;
        }
        for (int c = 0; c < C_DIM; ++c) {
            const float w_pre0 = wp0[c * C_DIM];
            const float w_pre1 = wp1[c * C_DIM];
#pragma unroll
            for (int k = 0; k < 4; ++k) {
                const float4 f  = in_lds[nbase + k][c];
                const float ws0 = wsc0p[k][c * C_DIM];
                const float ws1 = wsc1p[k][c * C_DIM];
                accS[k][0] += f.x * ws0;
                accS[k][1] += f.y * ws1;
                accS[k][2] += f.z * ws1;
                accS[k][3] += f.w * ws1;
                accP[k][0] += f.x * w_pre0;
                accP[k][1] += f.y * w_pre1;
                accP[k][2] += f.z * w_pre1;
                accP[k][3] += f.w * w_pre1;
            }
        }
    }

    float4* sc4 = (float4*)out_sc;
#pragma unroll
    for (int k = 0; k < 4; ++k) {
        const int n = nid[nbase + k];
        float4 o = {accS[k][0] * INV_C, accS[k][1] * INV_C,
                    accS[k][2] * INV_C, accS[k][3] * INV_C};
        sc4[n * C_DIM + d] = o;
        ushort4 p = {f2bf(accP[k][0] * INV_C), f2bf(accP[k][1] * INV_C),
                     f2bf(accP[k][2] * INV_C), f2bf(accP[k][3] * INV_C)};
        sv_bf[n * C_DIM + d] = p;
    }
}

// ---------------------------------------------------------------------------
// Kernel B: edge MLP -> per-edge 8-coefficient vector.
// ---------------------------------------------------------------------------
__global__ __launch_bounds__(256) void edge_mlp_kernel(
    const float* __restrict__ edge_feats,   // [E][8]
    const float* __restrict__ edge_attrs,   // [E][4]
    const float* __restrict__ W1,           // [8][64]
    const float* __restrict__ W2,           // [64][64]
    const float* __restrict__ W3,           // [64][4]
    float* __restrict__ coef)               // [E][8]
{
    __shared__ float h_lds[4][8][64];
    __shared__ float ef_lds[4][8][8];
    __shared__ float mix_lds[4][8][4];

    const int wave = threadIdx.x >> 6;
    const int lane = threadIdx.x & 63;
    const int base = (blockIdx.x * 4 + wave) * 8;

    ef_lds[wave][lane >> 3][lane & 7] = edge_feats[base * 8 + lane];
    __syncthreads();

    float acc1[8] = {};
    for (int k = 0; k < 8; ++k) {
        const float w = W1[k * 64 + lane];
#pragma unroll
        for (int e = 0; e < 8; ++e) acc1[e] += ef_lds[wave][e][k] * w;
    }
#pragma unroll
    for (int e = 0; e < 8; ++e) h_lds[wave][e][lane] = silu(acc1[e] * F_INV_SQRT8);
    __syncthreads();

    float acc2[8] = {};
    for (int k = 0; k < 64; ++k) {
        const float w = W2[k * 64 + lane];
#pragma unroll
        for (int e = 0; e < 8; ++e) acc2[e] += h_lds[wave][e][k] * w;
    }
    __syncthreads();
#pragma unroll
    for (int e = 0; e < 8; ++e) h_lds[wave][e][lane] = silu(acc2[e] * 0.125f);
    __syncthreads();

    if (lane < 32) {
        const int e = lane >> 2, m = lane & 3;
        float s = 0.0f;
        for (int k = 0; k < 64; ++k) s += h_lds[wave][e][k] * W3[k * 4 + m];
        mix_lds[wave][e][m] = s * 0.125f;
    }
    __syncthreads();

    const int e2 = lane >> 3, j = lane & 7;
    const float* mx = mix_lds[wave][e2];
    float v;
    if (j == 0)      v = mx[0];
    else if (j <= 3) v = mx[1] * edge_attrs[(base + e2) * 4 + j] * F_INV_SQRT3;
    else if (j == 4) v = mx[2];
    else             v = mx[3] * edge_attrs[(base + e2) * 4 + (j - 4)];
    coef[(base + e2) * 8 + j] = v;
}

// ---------------------------------------------------------------------------
// Kernel C1: CSR-gather aggregation. Writes bf16 GEMM A-matrices directly:
//   A_s[n][c*2+m]       = agg_s[n][c][m] / 16
//   A_v[n*3+i][c*2+m]   = agg_v[n][c][m][i] / 16
// ---------------------------------------------------------------------------
__global__ __launch_bounds__(256) void agg_kernel(
    const int* __restrict__ start,          // [N+1]
    const int* __restrict__ perm,           // [E]
    const int* __restrict__ senders,
    const float* __restrict__ coef,         // [E][8]
    const ushort4* __restrict__ sv_bf,      // [N][C] bf16x4
    unsigned int* __restrict__ A_s,         // [N][128] u32 (2x bf16)
    unsigned int* __restrict__ A_v)         // [3N][128] u32 (2x bf16)
{
    __shared__ int   se_lds[CHUNK];
    __shared__ float sc_lds[CHUNK][8];

    const int n0   = blockIdx.x * 8;
    const int t    = threadIdx.x;
    const int c    = t & 127;
    const int half = t >> 7;

    int nbeg[4], nend[4];
#pragma unroll
    for (int k = 0; k < 4; ++k) {
        nbeg[k] = start[n0 + half * 4 + k];
        nend[k] = start[n0 + half * 4 + k + 1];
    }

    const int blk_beg = start[n0];
    const int blk_end = start[n0 + 8];
    const float4* coef4 = (const float4*)coef;

    float acc[4][8] = {};

    for (int cb = blk_beg; cb < blk_end; cb += CHUNK) {
        const int cn = min(CHUNK, blk_end - cb);
        __syncthreads();
        for (int j = t; j < cn; j += 256) {
            const int e = perm[cb + j];
            se_lds[j] = senders[e];
            ((float4*)sc_lds[j])[0] = coef4[e * 2 + 0];
            ((float4*)sc_lds[j])[1] = coef4[e * 2 + 1];
        }
        __syncthreads();

#pragma unroll
        for (int k = 0; k < 4; ++k) {
            const int lo = max(nbeg[k], cb);
            const int hi = min(nend[k], cb + cn);
            int idx = lo;
            for (; idx + 2 <= hi; idx += 2) {
                const int j0 = idx - cb, j1 = j0 + 1;
                const int snd0 = se_lds[j0];
                const int snd1 = se_lds[j1];
                const ushort4 u0 = sv_bf[snd0 * C_DIM + c];
                const ushort4 u1 = sv_bf[snd1 * C_DIM + c];
                const float* kf0 = sc_lds[j0];
                const float* kf1 = sc_lds[j1];
                const float x0 = bf2f(u0.x), y0 = bf2f(u0.y),
                            z0 = bf2f(u0.z), w0 = bf2f(u0.w);
                const float x1 = bf2f(u1.x), y1 = bf2f(u1.y),
                            z1 = bf2f(u1.z), w1 = bf2f(u1.w);
                acc[k][0] += x0 * kf0[0];
                acc[k][1] += y0 * kf0[1] + z0 * kf0[2] + w0 * kf0[3];
                acc[k][2] += y0 * kf0[4];
                acc[k][3] += z0 * kf0[4];
                acc[k][4] += w0 * kf0[4];
                acc[k][5] += x0 * kf0[5];
                acc[k][6] += x0 * kf0[6];
                acc[k][7] += x0 * kf0[7];
                acc[k][0] += x1 * kf1[0];
                acc[k][1] += y1 * kf1[1] + z1 * kf1[2] + w1 * kf1[3];
                acc[k][2] += y1 * kf1[4];
                acc[k][3] += z1 * kf1[4];
                acc[k][4] += w1 * kf1[4];
                acc[k][5] += x1 * kf1[5];
                acc[k][6] += x1 * kf1[6];
                acc[k][7] += x1 * kf1[7];
            }
            if (idx < hi) {
                const int j = idx - cb;
                const int snd = se_lds[j];
                const ushort4 u = sv_bf[snd * C_DIM + c];
                const float* kf = sc_lds[j];
                const float x = bf2f(u.x), y = bf2f(u.y),
                            z = bf2f(u.z), w = bf2f(u.w);
                acc[k][0] += x * kf[0];
                acc[k][1] += y * kf[1] + z * kf[2] + w * kf[3];
                acc[k][2] += y * kf[4];
                acc[k][3] += z * kf[4];
                acc[k][4] += w * kf[4];
                acc[k][5] += x * kf[5];
                acc[k][6] += x * kf[6];
                acc[k][7] += x * kf[7];
            }
        }
    }

#pragma unroll
    for (int k = 0; k < 4; ++k) {
        const int n = n0 + half * 4 + k;
        A_s[n * 128 + c] = pack2bf(acc[k][0] * F_INV_AVG, acc[k][1] * F_INV_AVG);
        A_v[(n * 3 + 0) * 128 + c] =
            pack2bf(acc[k][2] * F_INV_AVG, acc[k][5] * F_INV_AVG);
        A_v[(n * 3 + 1) * 128 + c] =
            pack2bf(acc[k][3] * F_INV_AVG, acc[k][6] * F_INV_AVG);
        A_v[(n * 3 + 2) * 128 + c] =
            pack2bf(acc[k][4] * F_INV_AVG, acc[k][7] * F_INV_AVG);
    }
}

// ---------------------------------------------------------------------------
// W_post conversion: f32 [256][128] -> bf16 transposed [128][256], scale 1/16
// wait: scale INV_2C folded in.
// ---------------------------------------------------------------------------
__global__ __launch_bounds__(256) void wpost_convert_kernel(
    const float* __restrict__ W0, const float* __restrict__ W1,
    ushort* __restrict__ Bt0, ushort* __restrict__ Bt1)
{
    const int idx = blockIdx.x * 256 + threadIdx.x;   // 0 .. 32767
    const int k = idx >> 7, d = idx & 127;
    Bt0[d * 256 + k] = f2bf(W0[idx] * INV_2C);
    Bt1[d * 256 + k] = f2bf(W1[idx] * INV_2C);
}

// ---------------------------------------------------------------------------
// Kernel C2: MFMA GEMM  C[rows x 128] = A[rows x 256] @ Bt^T, scatter to out.
// 8 waves/block; wave w owns output cols [16w, 16w+16). B-frags in registers.
// rows_per_node==1: out[n*512 + d*4 + 0]        (scalar part)
// rows_per_node==3: out[(row/3)*512 + d*4 + 1 + row%3]  (vector part)
// Fragment layouts (m89/m91-verified): A row=lane&15, k=(lane>>4)*8+j;
// B col=lane&15 (via transposed Bt, contiguous 16B); D col=lane&15,
// row=(lane>>4)*4+reg.
// ---------------------------------------------------------------------------
__global__ __launch_bounds__(512) void post_gemm_kernel(
    const ushort* __restrict__ A,           // [rows][256] bf16
    const ushort* __restrict__ Bt,          // [128][256] bf16 (pre-scaled)
    float* __restrict__ out,                // [N][128][4]
    int ntiles, int rows_per_node, int comp_base)
{
    const int l  = threadIdx.x & 63;
    const int w  = threadIdx.x >> 6;        // wave id = col tile
    const int d0 = w * 16;
    const int lr = l & 15;
    const int lg = l >> 4;

    bf16x8 bfrag[8];
#pragma unroll
    for (int ks = 0; ks < 8; ++ks) {
        bfrag[ks] = *reinterpret_cast<const bf16x8*>(
            Bt + (size_t)(d0 + lr) * 256 + ks * 32 + lg * 8);
    }

    for (int tile = blockIdx.x; tile < ntiles; tile += gridDim.x) {
        const int r0 = tile * 16;
        f32x4 acc = {0.0f, 0.0f, 0.0f, 0.0f};
        const ushort* ap = A + (size_t)(r0 + lr) * 256 + lg * 8;
#pragma unroll
        for (int ks = 0; ks < 8; ++ks) {
            bf16x8 a = *reinterpret_cast<const bf16x8*>(ap + ks * 32);
            acc = __builtin_amdgcn_mfma_f32_16x16x32_bf16(a, bfrag[ks], acc,
                                                          0, 0, 0);
        }
#pragma unroll
        for (int r = 0; r < 4; ++r) {
            const int row = r0 + lg * 4 + r;
            int n, comp;
            if (rows_per_node == 1) { n = row; comp = 0; }
            else { n = row / 3; comp = comp_base + (row - n * 3); }
            out[(size_t)n * 512 + (d0 + lr) * 4 + comp] = acc[r];
        }
    }
}

// ---------------------------------------------------------------------------
extern "C" void kernel_launch(void* const* d_in, const int* in_sizes, int n_in,
                              void* d_out, int out_size, void* d_ws, size_t ws_size,
                              hipStream_t stream)
{
    const int*   specie     = (const int*)d_in[0];
    const float* node_feats = (const float*)d_in[1];
    const float* edge_attrs = (const float*)d_in[2];
    const float* edge_feats = (const float*)d_in[3];
    const int*   senders    = (const int*)d_in[4];
    const int*   receivers  = (const int*)d_in[5];
    const float* Wsc0  = (const float*)d_in[6];
    const float* Wsc1  = (const float*)d_in[7];
    const float* Wpre0 = (const float*)d_in[8];
    const float* Wpre1 = (const float*)d_in[9];
    const float* Wm1   = (const float*)d_in[10];
    const float* Wm2   = (const float*)d_in[11];
    const float* Wm3   = (const float*)d_in[12];
    const float* Wp0   = (const float*)d_in[13];
    const float* Wp1   = (const float*)d_in[14];

    float* out_node = (float*)d_out;                           // [N][C][4]
    float* out_sc   = out_node + (size_t)N_NODES * C_DIM * 4;  // [N][C][4]

    // workspace layout (bytes):
    //   sv_bf  [N][C] ushort4                 16 MB
    //   A_s    [N][128] u32                    8 MB
    //   A_v    [3N][128] u32                  24 MB
    //   coef   [E][8] f32                      8 MB
    //   Bt0,Bt1 [128][256] bf16                128 KB
    //   ints: counts/start/cursor/perm/spec   ~1.3 MB
    char* ws = (char*)d_ws;
    ushort4*      sv_bf = (ushort4*)ws;
    unsigned int* A_s   = (unsigned int*)(ws + (size_t)16 * 1024 * 1024);
    unsigned int* A_v   = A_s + (size_t)N_NODES * 128;
    float*        coef  = (float*)(A_v + (size_t)3 * N_NODES * 128);
    ushort*       Bt0   = (ushort*)(coef + (size_t)E_EDGES * 8);
    ushort*       Bt1   = Bt0 + 256 * 128;
    int* counts    = (int*)(Bt1 + 256 * 128);
    int* start     = counts + N_NODES;
    int* cursor    = start + (N_NODES + 1);
    int* perm      = cursor + N_NODES;
    int* scnt      = perm + E_EDGES;
    int* scur      = scnt + S_SPEC;
    int* node_perm = scur + S_SPEC;

    // --- CSR build (receiver -> edges) ---
    hipMemsetAsync(counts, 0, N_NODES * sizeof(int), stream);
    hipMemsetAsync(scnt, 0, S_SPEC * sizeof(int), stream);
    hist_kernel<<<E_EDGES / 256, 256, 0, stream>>>(receivers, counts);
    scan16k_kernel<<<1, 256, 0, stream>>>(counts, start);
    hipMemcpyAsync(cursor, start, N_NODES * sizeof(int),
                   hipMemcpyDeviceToDevice, stream);
    scatter_kernel<<<E_EDGES / 256, 256, 0, stream>>>(receivers, cursor, perm);

    // --- species sort of nodes ---
    spec_hist_kernel<<<N_NODES / 256, 256, 0, stream>>>(specie, scnt);
    spec_scan_kernel<<<1, 64, 0, stream>>>(scnt, scur);
    spec_scatter_kernel<<<N_NODES / 256, 256, 0, stream>>>(specie, scur, node_perm);

    // --- W_post -> bf16 transposed (scaled) ---
    wpost_convert_kernel<<<128, 256, 0, stream>>>(Wp0, Wp1, Bt0, Bt1);

    // --- node pre transforms (writes output 2: sc; sv as bf16) ---
    node_pre_kernel<<<N_NODES / 8, 256, 0, stream>>>(
        node_perm, specie, node_feats, Wsc0, Wsc1, Wpre0, Wpre1, out_sc, sv_bf);

    // --- edge MLP -> coefficients ---
    edge_mlp_kernel<<<E_EDGES / 32, 256, 0, stream>>>(
        edge_feats, edge_attrs, Wm1, Wm2, Wm3, coef);

    // --- gather-aggregate -> bf16 A matrices ---
    agg_kernel<<<N_NODES / 8, 256, 0, stream>>>(
        start, perm, senders, coef, sv_bf, A_s, A_v);

    // --- post GEMMs via MFMA (output 1) ---
    post_gemm_kernel<<<512, 512, 0, stream>>>(
        (const ushort*)A_s, Bt0, out_node, N_NODES / 16, 1, 0);
    post_gemm_kernel<<<1024, 512, 0, stream>>>(
        (const ushort*)A_v, Bt1, out_node, 3 * N_NODES / 16, 3, 1);
}

// Round 5
// 309.398 us; speedup vs baseline: 23.9829x; 1.1307x over previous
//
#include <hip/hip_runtime.h>
#include <hip/hip_bf16.h>

// Problem constants
#define N_NODES 16384
#define C_DIM   128
#define E_EDGES 262144
#define S_SPEC  10
#define CHUNK   256

__device__ __constant__ const float INV_C  = 0.08838834764831845f;  // 1/sqrt(128)
__device__ __constant__ const float INV_2C = 0.0625f;               // 1/sqrt(256)
#define F_INV_SQRT3 0.5773502691896258f
#define F_INV_SQRT8 0.35355339059327373f
#define F_INV_AVG   0.0625f   // 1/16 neighbors

typedef __attribute__((ext_vector_type(8))) short bf16x8;
typedef __attribute__((ext_vector_type(4))) float f32x4;

__device__ __forceinline__ float silu(float x) {
    return x / (1.0f + __expf(-x));
}

__device__ __forceinline__ unsigned short f2bf(float x) {
    __hip_bfloat16 h = __float2bfloat16(x);
    return *reinterpret_cast<unsigned short*>(&h);
}

__device__ __forceinline__ unsigned int pack2bf(float lo, float hi) {
    return (unsigned int)f2bf(lo) | ((unsigned int)f2bf(hi) << 16);
}

__device__ __forceinline__ float bf2f(unsigned short u) {
    return __uint_as_float(((unsigned int)u) << 16);
}

// ---------------------------------------------------------------------------
// CSR build (receiver -> edge list): histogram -> scan -> scatter perm
// ---------------------------------------------------------------------------
__global__ __launch_bounds__(256) void hist_kernel(
    const int* __restrict__ receivers, int* __restrict__ cnt)
{
    const int e = blockIdx.x * 256 + threadIdx.x;
    atomicAdd(&cnt[receivers[e]], 1);
}

__global__ __launch_bounds__(256) void scan16k_kernel(
    const int* __restrict__ cnt, int* __restrict__ start)
{
    __shared__ int sums[256];
    const int t = threadIdx.x;
    int s = 0;
    for (int i = 0; i < 64; ++i) s += cnt[t * 64 + i];
    sums[t] = s;
    __syncthreads();
    if (t == 0) {
        int a = 0;
        for (int i = 0; i < 256; ++i) { int v = sums[i]; sums[i] = a; a += v; }
    }
    __syncthreads();
    int a = sums[t];
    for (int i = 0; i < 64; ++i) {
        int v = cnt[t * 64 + i];
        start[t * 64 + i] = a;
        a += v;
    }
    if (t == 255) start[N_NODES] = a;
}

__global__ __launch_bounds__(256) void scatter_kernel(
    const int* __restrict__ receivers, int* __restrict__ cursor,
    int* __restrict__ perm)
{
    const int e = blockIdx.x * 256 + threadIdx.x;
    const int pos = atomicAdd(&cursor[receivers[e]], 1);
    perm[pos] = e;
}

// ---------------------------------------------------------------------------
// Species sort: 10-bin histogram -> scan -> scatter node_perm
// ---------------------------------------------------------------------------
__global__ __launch_bounds__(256) void spec_hist_kernel(
    const int* __restrict__ specie, int* __restrict__ scnt)
{
    __shared__ int h[S_SPEC];
    const int t = threadIdx.x;
    if (t < S_SPEC) h[t] = 0;
    __syncthreads();
    atomicAdd(&h[specie[blockIdx.x * 256 + t]], 1);
    __syncthreads();
    if (t < S_SPEC) atomicAdd(&scnt[t], h[t]);
}

__global__ void spec_scan_kernel(
    const int* __restrict__ scnt, int* __restrict__ scur)
{
    if (threadIdx.x == 0) {
        int a = 0;
        for (int i = 0; i < S_SPEC; ++i) { scur[i] = a; a += scnt[i]; }
    }
}

__global__ __launch_bounds__(256) void spec_scatter_kernel(
    const int* __restrict__ specie, int* __restrict__ scur,
    int* __restrict__ node_perm)
{
    const int n = blockIdx.x * 256 + threadIdx.x;
    const int pos = atomicAdd(&scur[specie[n]], 1);
    node_perm[pos] = n;
}

// ---------------------------------------------------------------------------
// Kernel A: per-node "pre" transforms, species-sorted node order.
// ---------------------------------------------------------------------------
__global__ __launch_bounds__(256) void node_pre_kernel(
    const int* __restrict__ node_perm,
    const int* __restrict__ specie,
    const float* __restrict__ node_feats,   // [N][C][4]
    const float* __restrict__ Wsc0,         // [S][C][C]
    const float* __restrict__ Wsc1,
    const float* __restrict__ Wpre0,        // [C][C]
    const float* __restrict__ Wpre1,
    float* __restrict__ out_sc,             // [N][C][4] (second output)
    ushort4* __restrict__ sv_bf)            // [N][C] bf16x4 workspace
{
    __shared__ float4 in_lds[8][C_DIM];
    __shared__ int nid[8];
    const int n0 = blockIdx.x * 8;
    const int t  = threadIdx.x;

    if (t < 8) nid[t] = node_perm[n0 + t];
    __syncthreads();

    const float4* nf4 = (const float4*)node_feats;
    for (int idx = t; idx < 8 * C_DIM; idx += 256) {
        int nn = idx >> 7, c = idx & 127;
        in_lds[nn][c] = nf4[nid[nn] * C_DIM + c];
    }
    __syncthreads();

    const int d     = t & 127;
    const int half  = t >> 7;
    const int nbase = half * 4;

    int sp[4];
#pragma unroll
    for (int k = 0; k < 4; ++k) sp[k] = specie[nid[nbase + k]];

    const float* wp0 = Wpre0 + d;
    const float* wp1 = Wpre1 + d;

    float accS[4][4] = {};
    float accP[4][4] = {};

    const bool same = (sp[0] == sp[1]) & (sp[1] == sp[2]) & (sp[2] == sp[3]);
    if (same) {
        const float* w0 = Wsc0 + sp[0] * C_DIM * C_DIM + d;
        const float* w1 = Wsc1 + sp[0] * C_DIM * C_DIM + d;
        for (int c = 0; c < C_DIM; ++c) {
            const float ws0    = w0[c * C_DIM];
            const float ws1    = w1[c * C_DIM];
            const float w_pre0 = wp0[c * C_DIM];
            const float w_pre1 = wp1[c * C_DIM];
#pragma unroll
            for (int k = 0; k < 4; ++k) {
                const float4 f = in_lds[nbase + k][c];
                accS[k][0] += f.x * ws0;
                accS[k][1] += f.y * ws1;
                accS[k][2] += f.z * ws1;
                accS[k][3] += f.w * ws1;
                accP[k][0] += f.x * w_pre0;
                accP[k][1] += f.y * w_pre1;
                accP[k][2] += f.z * w_pre1;
                accP[k][3] += f.w * w_pre1;
            }
        }
    } else {
        const float* wsc0p[4];
        const float* wsc1p[4];
#pragma unroll
        for (int k = 0; k < 4; ++k) {
            wsc0p[k] = Wsc0 + sp[k] * C_DIM * C_DIM + d;
            wsc1p[k] = Wsc1 + sp[k] * C_DIM * C_DIM + d;
        }
        for (int c = 0; c < C_DIM; ++c) {
            const float w_pre0 = wp0[c * C_DIM];
            const float w_pre1 = wp1[c * C_DIM];
#pragma unroll
            for (int k = 0; k < 4; ++k) {
                const float4 f  = in_lds[nbase + k][c];
                const float ws0 = wsc0p[k][c * C_DIM];
                const float ws1 = wsc1p[k][c * C_DIM];
                accS[k][0] += f.x * ws0;
                accS[k][1] += f.y * ws1;
                accS[k][2] += f.z * ws1;
                accS[k][3] += f.w * ws1;
                accP[k][0] += f.x * w_pre0;
                accP[k][1] += f.y * w_pre1;
                accP[k][2] += f.z * w_pre1;
                accP[k][3] += f.w * w_pre1;
            }
        }
    }

    float4* sc4 = (float4*)out_sc;
#pragma unroll
    for (int k = 0; k < 4; ++k) {
        const int n = nid[nbase + k];
        float4 o = {accS[k][0] * INV_C, accS[k][1] * INV_C,
                    accS[k][2] * INV_C, accS[k][3] * INV_C};
        sc4[n * C_DIM + d] = o;
        ushort4 p = {f2bf(accP[k][0] * INV_C), f2bf(accP[k][1] * INV_C),
                     f2bf(accP[k][2] * INV_C), f2bf(accP[k][3] * INV_C)};
        sv_bf[n * C_DIM + d] = p;
    }
}

// ---------------------------------------------------------------------------
// MLP weight prep: transpose + pad + fold scales -> bf16.
//   W1t[64][32]: W1t[h][k] = k<8 ? W1[k][h]*INV_SQRT8 : 0
//   W2t[64][64]: W2t[c][k] = W2[k][c]*0.125
//   W3t[16][64]: W3t[m][k] = m<4 ? W3[k][m]*0.125 : 0
// ---------------------------------------------------------------------------
__global__ __launch_bounds__(256) void wmlp_convert_kernel(
    const float* __restrict__ W1, const float* __restrict__ W2,
    const float* __restrict__ W3,
    ushort* __restrict__ W1t, ushort* __restrict__ W2t,
    ushort* __restrict__ W3t)
{
    const int idx = blockIdx.x * 256 + threadIdx.x;   // 0..4095
    if (idx < 2048) {
        const int h = idx >> 5, k = idx & 31;
        W1t[idx] = (k < 8) ? f2bf(W1[k * 64 + h] * F_INV_SQRT8) : (ushort)0;
    }
    {
        const int c = idx >> 6, k = idx & 63;
        W2t[idx] = f2bf(W2[k * 64 + c] * 0.125f);
    }
    if (idx < 1024) {
        const int m = idx >> 6, k = idx & 63;
        W3t[idx] = (m < 4) ? f2bf(W3[k * 4 + m] * 0.125f) : (ushort)0;
    }
}

// ---------------------------------------------------------------------------
// Kernel B: edge MLP via MFMA. One wave = 16 edges. All layers computed in
// swapped orientation D = W^T · h^T so D cols = edges (lane&15) and LDS
// round-trips are vector ops (ds_write_b64 / ds_read_b128).
// Scales folded into weights; D3 = mix directly.
// ---------------------------------------------------------------------------
__global__ __launch_bounds__(256) void edge_mlp_mfma_kernel(
    const float* __restrict__ edge_feats,   // [E][8]
    const float* __restrict__ edge_attrs,   // [E][4]
    const ushort* __restrict__ W1t,         // [64][32] bf16 (padded, scaled)
    const ushort* __restrict__ W2t,         // [64][64] bf16 (scaled)
    const ushort* __restrict__ W3t,         // [16][64] bf16 (padded, scaled)
    float* __restrict__ coef)               // [E][8]
{
    __shared__ ushort h_lds[4][16][72];     // per-wave [edge][hidden], padded

    const int w  = threadIdx.x >> 6;
    const int l  = threadIdx.x & 63;
    const int lr = l & 15;
    const int lg = l >> 4;

    // Persistent weight A-frags: row = tile*16+lr, k = (ks*32)+lg*8+j
    bf16x8 a1[4];
#pragma unroll
    for (int mt = 0; mt < 4; ++mt)
        a1[mt] = *reinterpret_cast<const bf16x8*>(
            W1t + (mt * 16 + lr) * 32 + lg * 8);
    bf16x8 a2[4][2];
#pragma unroll
    for (int mt = 0; mt < 4; ++mt)
#pragma unroll
        for (int ks = 0; ks < 2; ++ks)
            a2[mt][ks] = *reinterpret_cast<const bf16x8*>(
                W2t + (mt * 16 + lr) * 64 + ks * 32 + lg * 8);
    bf16x8 a3[2];
#pragma unroll
    for (int ks = 0; ks < 2; ++ks)
        a3[ks] = *reinterpret_cast<const bf16x8*>(
            W3t + lr * 64 + ks * 32 + lg * 8);

    const int tile = blockIdx.x * 4 + w;
    const int e0   = tile * 16;
    const f32x4 zero = {0.0f, 0.0f, 0.0f, 0.0f};

    // ---- layer 1: D1[h][e] = W1t · ef^T.  B-frag: col=edge=lr, k=lg*8+j
    // (only k<8 real -> lg==0 lanes carry data, others zero).
    bf16x8 b1 = {0, 0, 0, 0, 0, 0, 0, 0};
    if (lg == 0) {
        const float4 q0 = *(const float4*)(edge_feats + (size_t)(e0 + lr) * 8);
        const float4 q1 = *(const float4*)(edge_feats + (size_t)(e0 + lr) * 8 + 4);
        b1[0] = (short)f2bf(q0.x); b1[1] = (short)f2bf(q0.y);
        b1[2] = (short)f2bf(q0.z); b1[3] = (short)f2bf(q0.w);
        b1[4] = (short)f2bf(q1.x); b1[5] = (short)f2bf(q1.y);
        b1[6] = (short)f2bf(q1.z); b1[7] = (short)f2bf(q1.w);
    }

    f32x4 d1[4];
#pragma unroll
    for (int mt = 0; mt < 4; ++mt)
        d1[mt] = __builtin_amdgcn_mfma_f32_16x16x32_bf16(a1[mt], b1, zero, 0, 0, 0);

    // silu + pack + store h1: lane holds rows h=mt*16+lg*4+r for edge lr.
#pragma unroll
    for (int mt = 0; mt < 4; ++mt) {
        uint2 p;
        p.x = pack2bf(silu(d1[mt][0]), silu(d1[mt][1]));
        p.y = pack2bf(silu(d1[mt][2]), silu(d1[mt][3]));
        *reinterpret_cast<uint2*>(&h_lds[w][lr][mt * 16 + lg * 4]) = p;
    }
    __syncthreads();

    // ---- layer 2: D2[c][e] = W2t · h1^T.  B-frag from LDS (b128 reads).
    bf16x8 b2[2];
#pragma unroll
    for (int ks = 0; ks < 2; ++ks)
        b2[ks] = *reinterpret_cast<const bf16x8*>(
            &h_lds[w][lr][ks * 32 + lg * 8]);

    f32x4 d2[4];
#pragma unroll
    for (int mt = 0; mt < 4; ++mt) {
        d2[mt] = __builtin_amdgcn_mfma_f32_16x16x32_bf16(a2[mt][0], b2[0], zero, 0, 0, 0);
        d2[mt] = __builtin_amdgcn_mfma_f32_16x16x32_bf16(a2[mt][1], b2[1], d2[mt], 0, 0, 0);
    }

#pragma unroll
    for (int mt = 0; mt < 4; ++mt) {
        uint2 p;
        p.x = pack2bf(silu(d2[mt][0]), silu(d2[mt][1]));
        p.y = pack2bf(silu(d2[mt][2]), silu(d2[mt][3]));
        *reinterpret_cast<uint2*>(&h_lds[w][lr][mt * 16 + lg * 4]) = p;
    }
    __syncthreads();

    // ---- layer 3: D3[m][e] = W3t · h2^T (m valid 0..3).
    bf16x8 b3[2];
#pragma unroll
    for (int ks = 0; ks < 2; ++ks)
        b3[ks] = *reinterpret_cast<const bf16x8*>(
            &h_lds[w][lr][ks * 32 + lg * 8]);

    f32x4 d3;
    d3 = __builtin_amdgcn_mfma_f32_16x16x32_bf16(a3[0], b3[0], zero, 0, 0, 0);
    d3 = __builtin_amdgcn_mfma_f32_16x16x32_bf16(a3[1], b3[1], d3, 0, 0, 0);

    // lanes lg==0 hold mix[e0+lr][m] in d3[m]; expand to 8 coefs.
    if (lg == 0) {
        const int e = e0 + lr;
        const float4 a = *(const float4*)(edge_attrs + (size_t)e * 4);
        const float mx0 = d3[0], mx1 = d3[1], mx2 = d3[2], mx3 = d3[3];
        float4 c0 = {mx0, mx1 * a.y * F_INV_SQRT3,
                     mx1 * a.z * F_INV_SQRT3, mx1 * a.w * F_INV_SQRT3};
        float4 c1 = {mx2, mx3 * a.y, mx3 * a.z, mx3 * a.w};
        ((float4*)coef)[e * 2 + 0] = c0;
        ((float4*)coef)[e * 2 + 1] = c1;
    }
}

// ---------------------------------------------------------------------------
// Kernel C1: CSR-gather aggregation. Writes bf16 GEMM A-matrices directly.
// ---------------------------------------------------------------------------
__global__ __launch_bounds__(256) void agg_kernel(
    const int* __restrict__ start,          // [N+1]
    const int* __restrict__ perm,           // [E]
    const int* __restrict__ senders,
    const float* __restrict__ coef,         // [E][8]
    const ushort4* __restrict__ sv_bf,      // [N][C] bf16x4
    unsigned int* __restrict__ A_s,         // [N][128] u32 (2x bf16)
    unsigned int* __restrict__ A_v)         // [3N][128] u32 (2x bf16)
{
    __shared__ int   se_lds[CHUNK];
    __shared__ float sc_lds[CHUNK][8];

    const int n0   = blockIdx.x * 8;
    const int t    = threadIdx.x;
    const int c    = t & 127;
    const int half = t >> 7;

    int nbeg[4], nend[4];
#pragma unroll
    for (int k = 0; k < 4; ++k) {
        nbeg[k] = start[n0 + half * 4 + k];
        nend[k] = start[n0 + half * 4 + k + 1];
    }

    const int blk_beg = start[n0];
    const int blk_end = start[n0 + 8];
    const float4* coef4 = (const float4*)coef;

    float acc[4][8] = {};

    for (int cb = blk_beg; cb < blk_end; cb += CHUNK) {
        const int cn = min(CHUNK, blk_end - cb);
        __syncthreads();
        for (int j = t; j < cn; j += 256) {
            const int e = perm[cb + j];
            se_lds[j] = senders[e];
            ((float4*)sc_lds[j])[0] = coef4[e * 2 + 0];
            ((float4*)sc_lds[j])[1] = coef4[e * 2 + 1];
        }
        __syncthreads();

#pragma unroll
        for (int k = 0; k < 4; ++k) {
            const int lo = max(nbeg[k], cb);
            const int hi = min(nend[k], cb + cn);
            int idx = lo;
            for (; idx + 2 <= hi; idx += 2) {
                const int j0 = idx - cb, j1 = j0 + 1;
                const int snd0 = se_lds[j0];
                const int snd1 = se_lds[j1];
                const ushort4 u0 = sv_bf[snd0 * C_DIM + c];
                const ushort4 u1 = sv_bf[snd1 * C_DIM + c];
                const float* kf0 = sc_lds[j0];
                const float* kf1 = sc_lds[j1];
                const float x0 = bf2f(u0.x), y0 = bf2f(u0.y),
                            z0 = bf2f(u0.z), w0 = bf2f(u0.w);
                const float x1 = bf2f(u1.x), y1 = bf2f(u1.y),
                            z1 = bf2f(u1.z), w1 = bf2f(u1.w);
                acc[k][0] += x0 * kf0[0];
                acc[k][1] += y0 * kf0[1] + z0 * kf0[2] + w0 * kf0[3];
                acc[k][2] += y0 * kf0[4];
                acc[k][3] += z0 * kf0[4];
                acc[k][4] += w0 * kf0[4];
                acc[k][5] += x0 * kf0[5];
                acc[k][6] += x0 * kf0[6];
                acc[k][7] += x0 * kf0[7];
                acc[k][0] += x1 * kf1[0];
                acc[k][1] += y1 * kf1[1] + z1 * kf1[2] + w1 * kf1[3];
                acc[k][2] += y1 * kf1[4];
                acc[k][3] += z1 * kf1[4];
                acc[k][4] += w1 * kf1[4];
                acc[k][5] += x1 * kf1[5];
                acc[k][6] += x1 * kf1[6];
                acc[k][7] += x1 * kf1[7];
            }
            if (idx < hi) {
                const int j = idx - cb;
                const int snd = se_lds[j];
                const ushort4 u = sv_bf[snd * C_DIM + c];
                const float* kf = sc_lds[j];
                const float x = bf2f(u.x), y = bf2f(u.y),
                            z = bf2f(u.z), w = bf2f(u.w);
                acc[k][0] += x * kf[0];
                acc[k][1] += y * kf[1] + z * kf[2] + w * kf[3];
                acc[k][2] += y * kf[4];
                acc[k][3] += z * kf[4];
                acc[k][4] += w * kf[4];
                acc[k][5] += x * kf[5];
                acc[k][6] += x * kf[6];
                acc[k][7] += x * kf[7];
            }
        }
    }

#pragma unroll
    for (int k = 0; k < 4; ++k) {
        const int n = n0 + half * 4 + k;
        A_s[n * 128 + c] = pack2bf(acc[k][0] * F_INV_AVG, acc[k][1] * F_INV_AVG);
        A_v[(n * 3 + 0) * 128 + c] =
            pack2bf(acc[k][2] * F_INV_AVG, acc[k][5] * F_INV_AVG);
        A_v[(n * 3 + 1) * 128 + c] =
            pack2bf(acc[k][3] * F_INV_AVG, acc[k][6] * F_INV_AVG);
        A_v[(n * 3 + 2) * 128 + c] =
            pack2bf(acc[k][4] * F_INV_AVG, acc[k][7] * F_INV_AVG);
    }
}

// ---------------------------------------------------------------------------
// W_post conversion: f32 [256][128] -> bf16 transposed [128][256], INV_2C in.
// ---------------------------------------------------------------------------
__global__ __launch_bounds__(256) void wpost_convert_kernel(
    const float* __restrict__ W0, const float* __restrict__ W1,
    ushort* __restrict__ Bt0, ushort* __restrict__ Bt1)
{
    const int idx = blockIdx.x * 256 + threadIdx.x;   // 0 .. 32767
    const int k = idx >> 7, d = idx & 127;
    Bt0[d * 256 + k] = f2bf(W0[idx] * INV_2C);
    Bt1[d * 256 + k] = f2bf(W1[idx] * INV_2C);
}

// ---------------------------------------------------------------------------
// Kernel C2: MFMA GEMM  C[rows x 128] = A[rows x 256] @ Bt^T, scatter to out.
// ---------------------------------------------------------------------------
__global__ __launch_bounds__(512) void post_gemm_kernel(
    const ushort* __restrict__ A,           // [rows][256] bf16
    const ushort* __restrict__ Bt,          // [128][256] bf16 (pre-scaled)
    float* __restrict__ out,                // [N][128][4]
    int ntiles, int rows_per_node, int comp_base)
{
    const int l  = threadIdx.x & 63;
    const int w  = threadIdx.x >> 6;        // wave id = col tile
    const int d0 = w * 16;
    const int lr = l & 15;
    const int lg = l >> 4;

    bf16x8 bfrag[8];
#pragma unroll
    for (int ks = 0; ks < 8; ++ks) {
        bfrag[ks] = *reinterpret_cast<const bf16x8*>(
            Bt + (size_t)(d0 + lr) * 256 + ks * 32 + lg * 8);
    }

    for (int tile = blockIdx.x; tile < ntiles; tile += gridDim.x) {
        const int r0 = tile * 16;
        f32x4 acc = {0.0f, 0.0f, 0.0f, 0.0f};
        const ushort* ap = A + (size_t)(r0 + lr) * 256 + lg * 8;
#pragma unroll
        for (int ks = 0; ks < 8; ++ks) {
            bf16x8 a = *reinterpret_cast<const bf16x8*>(ap + ks * 32);
            acc = __builtin_amdgcn_mfma_f32_16x16x32_bf16(a, bfrag[ks], acc,
                                                          0, 0, 0);
        }
#pragma unroll
        for (int r = 0; r < 4; ++r) {
            const int row = r0 + lg * 4 + r;
            int n, comp;
            if (rows_per_node == 1) { n = row; comp = 0; }
            else { n = row / 3; comp = comp_base + (row - n * 3); }
            out[(size_t)n * 512 + (d0 + lr) * 4 + comp] = acc[r];
        }
    }
}

// ---------------------------------------------------------------------------
extern "C" void kernel_launch(void* const* d_in, const int* in_sizes, int n_in,
                              void* d_out, int out_size, void* d_ws, size_t ws_size,
                              hipStream_t stream)
{
    const int*   specie     = (const int*)d_in[0];
    const float* node_feats = (const float*)d_in[1];
    const float* edge_attrs = (const float*)d_in[2];
    const float* edge_feats = (const float*)d_in[3];
    const int*   senders    = (const int*)d_in[4];
    const int*   receivers  = (const int*)d_in[5];
    const float* Wsc0  = (const float*)d_in[6];
    const float* Wsc1  = (const float*)d_in[7];
    const float* Wpre0 = (const float*)d_in[8];
    const float* Wpre1 = (const float*)d_in[9];
    const float* Wm1   = (const float*)d_in[10];
    const float* Wm2   = (const float*)d_in[11];
    const float* Wm3   = (const float*)d_in[12];
    const float* Wp0   = (const float*)d_in[13];
    const float* Wp1   = (const float*)d_in[14];

    float* out_node = (float*)d_out;                           // [N][C][4]
    float* out_sc   = out_node + (size_t)N_NODES * C_DIM * 4;  // [N][C][4]

    // workspace layout
    char* ws = (char*)d_ws;
    ushort4*      sv_bf = (ushort4*)ws;                               // 16 MB
    unsigned int* A_s   = (unsigned int*)(ws + (size_t)16 * 1024 * 1024);
    unsigned int* A_v   = A_s + (size_t)N_NODES * 128;
    float*        coef  = (float*)(A_v + (size_t)3 * N_NODES * 128);
    ushort*       Bt0   = (ushort*)(coef + (size_t)E_EDGES * 8);
    ushort*       Bt1   = Bt0 + 256 * 128;
    ushort*       W1t   = Bt1 + 256 * 128;     // [64][32]
    ushort*       W2t   = W1t + 64 * 32;       // [64][64]
    ushort*       W3t   = W2t + 64 * 64;       // [16][64]
    int* counts    = (int*)(W3t + 16 * 64);
    int* start     = counts + N_NODES;
    int* cursor    = start + (N_NODES + 1);
    int* perm      = cursor + N_NODES;
    int* scnt      = perm + E_EDGES;
    int* scur      = scnt + S_SPEC;
    int* node_perm = scur + S_SPEC;

    // --- CSR build (receiver -> edges) ---
    hipMemsetAsync(counts, 0, N_NODES * sizeof(int), stream);
    hipMemsetAsync(scnt, 0, S_SPEC * sizeof(int), stream);
    hist_kernel<<<E_EDGES / 256, 256, 0, stream>>>(receivers, counts);
    scan16k_kernel<<<1, 256, 0, stream>>>(counts, start);
    hipMemcpyAsync(cursor, start, N_NODES * sizeof(int),
                   hipMemcpyDeviceToDevice, stream);
    scatter_kernel<<<E_EDGES / 256, 256, 0, stream>>>(receivers, cursor, perm);

    // --- species sort of nodes ---
    spec_hist_kernel<<<N_NODES / 256, 256, 0, stream>>>(specie, scnt);
    spec_scan_kernel<<<1, 64, 0, stream>>>(scnt, scur);
    spec_scatter_kernel<<<N_NODES / 256, 256, 0, stream>>>(specie, scur, node_perm);

    // --- weight conversions (bf16, transposed, scales folded) ---
    wpost_convert_kernel<<<128, 256, 0, stream>>>(Wp0, Wp1, Bt0, Bt1);
    wmlp_convert_kernel<<<16, 256, 0, stream>>>(Wm1, Wm2, Wm3, W1t, W2t, W3t);

    // --- node pre transforms (writes output 2: sc; sv as bf16) ---
    node_pre_kernel<<<N_NODES / 8, 256, 0, stream>>>(
        node_perm, specie, node_feats, Wsc0, Wsc1, Wpre0, Wpre1, out_sc, sv_bf);

    // --- edge MLP via MFMA -> coefficients ---
    edge_mlp_mfma_kernel<<<E_EDGES / 64, 256, 0, stream>>>(
        edge_feats, edge_attrs, W1t, W2t, W3t, coef);

    // --- gather-aggregate -> bf16 A matrices ---
    agg_kernel<<<N_NODES / 8, 256, 0, stream>>>(
        start, perm, senders, coef, sv_bf, A_s, A_v);

    // --- post GEMMs via MFMA (output 1) ---
    post_gemm_kernel<<<512, 512, 0, stream>>>(
        (const ushort*)A_s, Bt0, out_node, N_NODES / 16, 1, 0);
    post_gemm_kernel<<<1024, 512, 0, stream>>>(
        (const ushort*)A_v, Bt1, out_node, 3 * N_NODES / 16, 3, 1);
}